// Round 1
// baseline (1060.044 us; speedup 1.0000x reference)
//
#include <hip/hip_runtime.h>
#include <cstdint>
#include <cstddef>

#define NE   384
#define NH   6
#define NKV  3
#define HD   64
#define BSZ  8
#define SEQ  2048
#define MROWS (BSZ*SEQ)

// ---------------------------------------------------------------------------
// Fused QKV projection: y = x @ W.T + b for Wq/Wk/Wv concatenated along N.
// Tile 64x64, BK=16, 256 threads, 4x4 micro-tile per thread.
// Writes Q as [B,NH,T,D], K/V as [B,NKV,T,D].
// ---------------------------------------------------------------------------
__global__ __launch_bounds__(256) void qkv_proj_kernel(
    const float* __restrict__ x,
    const float* __restrict__ Wq, const float* __restrict__ bq,
    const float* __restrict__ Wk, const float* __restrict__ bk,
    const float* __restrict__ Wv, const float* __restrict__ bv,
    float* __restrict__ Qb, float* __restrict__ Kb, float* __restrict__ Vb)
{
    __shared__ float As[16][68];   // [k][m], pad->68 keeps 16B alignment per row
    __shared__ float Bs[16][68];   // [k][n]
    const int tid = threadIdx.x;
    const int m0 = blockIdx.x * 64;
    const int n0 = blockIdx.y * 64;   // 0..767: [0,384)=Q, [384,576)=K, [576,768)=V

    const float* Wrow; const float* bias;
    float* buf; int nh; int hh;
    if (n0 < 384)      { Wrow = Wq + (size_t)n0*NE;       bias = bq + n0;       buf = Qb; nh = NH;  hh = n0 >> 6; }
    else if (n0 < 576) { Wrow = Wk + (size_t)(n0-384)*NE; bias = bk + (n0-384); buf = Kb; nh = NKV; hh = (n0-384) >> 6; }
    else               { Wrow = Wv + (size_t)(n0-576)*NE; bias = bv + (n0-576); buf = Vb; nh = NKV; hh = (n0-576) >> 6; }

    const int lrow = tid >> 2;     // 0..63
    const int lc   = tid & 3;      // 0..3 (float4 column)
    const int tr   = tid >> 4;     // 0..15 row group
    const int tc   = tid & 15;     // 0..15 col group

    float acc[4][4] = {};

    for (int k0 = 0; k0 < NE; k0 += 16) {
        float4 xa = *reinterpret_cast<const float4*>(&x[(size_t)(m0 + lrow)*NE + k0 + lc*4]);
        float4 wa = *reinterpret_cast<const float4*>(&Wrow[(size_t)lrow*NE + k0 + lc*4]);
        __syncthreads();
        As[lc*4+0][lrow] = xa.x; As[lc*4+1][lrow] = xa.y;
        As[lc*4+2][lrow] = xa.z; As[lc*4+3][lrow] = xa.w;
        Bs[lc*4+0][lrow] = wa.x; Bs[lc*4+1][lrow] = wa.y;
        Bs[lc*4+2][lrow] = wa.z; Bs[lc*4+3][lrow] = wa.w;
        __syncthreads();
        #pragma unroll
        for (int kk = 0; kk < 16; ++kk) {
            float4 a4 = *reinterpret_cast<const float4*>(&As[kk][tr*4]);
            float4 b4 = *reinterpret_cast<const float4*>(&Bs[kk][tc*4]);
            float av[4] = {a4.x, a4.y, a4.z, a4.w};
            float bv4[4] = {b4.x, b4.y, b4.z, b4.w};
            #pragma unroll
            for (int i = 0; i < 4; ++i)
                #pragma unroll
                for (int j = 0; j < 4; ++j)
                    acc[i][j] = fmaf(av[i], bv4[j], acc[i][j]);
        }
    }

    float4 bias4 = *reinterpret_cast<const float4*>(&bias[tc*4]);
    const float bb4[4] = {bias4.x, bias4.y, bias4.z, bias4.w};
    #pragma unroll
    for (int i = 0; i < 4; ++i) {
        int m = m0 + tr*4 + i;
        int b = m >> 11;          // /SEQ
        int t = m & 2047;         // %SEQ
        float4 v4;
        v4.x = acc[i][0] + bb4[0];
        v4.y = acc[i][1] + bb4[1];
        v4.z = acc[i][2] + bb4[2];
        v4.w = acc[i][3] + bb4[3];
        *reinterpret_cast<float4*>(&buf[(((size_t)b*nh + hh)*SEQ + t)*HD + tc*4]) = v4;
    }
}

// ---------------------------------------------------------------------------
// Flash-style causal attention, fp32. One block = (b, h, 64-row q-tile).
// 256 threads; S and PV both 64x64x64 micro-GEMMs (4x4 per thread).
// Online softmax with running (m, l) per q-row, reduced across the 16 lanes
// of each row group via __shfl_xor. P reuses K's LDS (keeps static LDS <64KB).
// Scale is 1/sqrt(NE) per the reference (NOT 1/sqrt(head_dim)).
// ---------------------------------------------------------------------------
__global__ __launch_bounds__(256) void attn_kernel(
    const float* __restrict__ Qb, const float* __restrict__ Kb,
    const float* __restrict__ Vb, float* __restrict__ Ab)
{
    __shared__ float Qs[64][68];    // [d][m]
    __shared__ float KPs[64][68];   // K tile as [d][n]; reused as P [n][m]
    __shared__ float Vs[64][68];    // [n][d]

    const int tid = threadIdx.x;
    const int qtile = (SEQ/64 - 1) - blockIdx.x;   // heavy tiles launch first
    const int qt0 = qtile * 64;
    const int h = blockIdx.y;
    const int b = blockIdx.z;
    const int kvh = h >> 1;                        // interleaved repeat_kv

    const float* Qbase = Qb + (((size_t)b*NH + h)*SEQ + qt0)*HD;
    const float* Kbase = Kb + ((size_t)b*NKV + kvh)*SEQ*HD;
    const float* Vbase = Vb + ((size_t)b*NKV + kvh)*SEQ*HD;

    // Load Q tile transposed: Qs[d][m]
    #pragma unroll
    for (int i = 0; i < 4; ++i) {
        int flat = tid + i*256;            // 0..1023
        int row = flat >> 4, c = flat & 15;
        float4 q4 = *reinterpret_cast<const float4*>(&Qbase[(size_t)row*HD + c*4]);
        Qs[c*4+0][row] = q4.x; Qs[c*4+1][row] = q4.y;
        Qs[c*4+2][row] = q4.z; Qs[c*4+3][row] = q4.w;
    }

    const int tr = tid >> 4, tc = tid & 15;
    float o[4][4] = {};
    float mrun[4], lrun[4];
    #pragma unroll
    for (int i = 0; i < 4; ++i) { mrun[i] = -1e30f; lrun[i] = 0.f; }
    const float scale = 1.0f / sqrtf((float)NE);

    const int ntiles = qtile + 1;
    for (int jt = 0; jt < ntiles; ++jt) {
        const int j0 = jt * 64;
        __syncthreads();   // prev iter's PV reads of KPs/Vs complete
        #pragma unroll
        for (int i = 0; i < 4; ++i) {
            int flat = tid + i*256;
            int row = flat >> 4, c = flat & 15;
            float4 k4 = *reinterpret_cast<const float4*>(&Kbase[(size_t)(j0+row)*HD + c*4]);
            KPs[c*4+0][row] = k4.x; KPs[c*4+1][row] = k4.y;
            KPs[c*4+2][row] = k4.z; KPs[c*4+3][row] = k4.w;
            float4 v4 = *reinterpret_cast<const float4*>(&Vbase[(size_t)(j0+row)*HD + c*4]);
            *reinterpret_cast<float4*>(&Vs[row][c*4]) = v4;
        }
        __syncthreads();   // K/V staged

        // S = Q K^T  (over d)
        float s[4][4] = {};
        #pragma unroll
        for (int kk = 0; kk < 64; ++kk) {
            float4 a4 = *reinterpret_cast<const float4*>(&Qs[kk][tr*4]);
            float4 b4 = *reinterpret_cast<const float4*>(&KPs[kk][tc*4]);
            float av[4] = {a4.x, a4.y, a4.z, a4.w};
            float bv4[4] = {b4.x, b4.y, b4.z, b4.w};
            #pragma unroll
            for (int i = 0; i < 4; ++i)
                #pragma unroll
                for (int j = 0; j < 4; ++j)
                    s[i][j] = fmaf(av[i], bv4[j], s[i][j]);
        }
        #pragma unroll
        for (int i = 0; i < 4; ++i)
            #pragma unroll
            for (int j = 0; j < 4; ++j)
                s[i][j] *= scale;
        if (j0 == qt0) {   // only the diagonal tile needs masking
            #pragma unroll
            for (int i = 0; i < 4; ++i)
                #pragma unroll
                for (int j = 0; j < 4; ++j)
                    if (tc*4 + j > tr*4 + i) s[i][j] = -1e30f;
        }

        // Online softmax: row stats across the 16 tc-lanes of this tr group
        #pragma unroll
        for (int i = 0; i < 4; ++i) {
            float mx = fmaxf(fmaxf(s[i][0], s[i][1]), fmaxf(s[i][2], s[i][3]));
            mx = fmaxf(mx, __shfl_xor(mx, 1));
            mx = fmaxf(mx, __shfl_xor(mx, 2));
            mx = fmaxf(mx, __shfl_xor(mx, 4));
            mx = fmaxf(mx, __shfl_xor(mx, 8));
            float mnew = fmaxf(mrun[i], mx);
            float corr = __expf(mrun[i] - mnew);
            float rs = 0.f;
            #pragma unroll
            for (int j = 0; j < 4; ++j) {
                float p = __expf(s[i][j] - mnew);
                s[i][j] = p;
                rs += p;
            }
            rs += __shfl_xor(rs, 1);
            rs += __shfl_xor(rs, 2);
            rs += __shfl_xor(rs, 4);
            rs += __shfl_xor(rs, 8);
            lrun[i] = lrun[i]*corr + rs;
            mrun[i] = mnew;
            o[i][0] *= corr; o[i][1] *= corr; o[i][2] *= corr; o[i][3] *= corr;
        }

        __syncthreads();   // all S-gemm reads of KPs done; safe to overwrite as P
        #pragma unroll
        for (int i = 0; i < 4; ++i)
            #pragma unroll
            for (int j = 0; j < 4; ++j)
                KPs[tc*4+j][tr*4+i] = s[i][j];   // P transposed: [n][m]
        __syncthreads();   // P staged

        // O += P V  (over n)
        #pragma unroll
        for (int kk = 0; kk < 64; ++kk) {
            float4 a4 = *reinterpret_cast<const float4*>(&KPs[kk][tr*4]);
            float4 b4 = *reinterpret_cast<const float4*>(&Vs[kk][tc*4]);
            float av[4] = {a4.x, a4.y, a4.z, a4.w};
            float bv4[4] = {b4.x, b4.y, b4.z, b4.w};
            #pragma unroll
            for (int i = 0; i < 4; ++i)
                #pragma unroll
                for (int j = 0; j < 4; ++j)
                    o[i][j] = fmaf(av[i], bv4[j], o[i][j]);
        }
    }

    // normalize + write attention output as [B,T,NE] for the out-projection
    #pragma unroll
    for (int i = 0; i < 4; ++i) {
        float inv = 1.0f / lrun[i];
        int t = qt0 + tr*4 + i;
        float4 v4;
        v4.x = o[i][0]*inv; v4.y = o[i][1]*inv;
        v4.z = o[i][2]*inv; v4.w = o[i][3]*inv;
        *reinterpret_cast<float4*>(&Ab[((size_t)b*SEQ + t)*NE + h*HD + tc*4]) = v4;
    }
}

// ---------------------------------------------------------------------------
// Output projection: out = A @ Wo.T + bo.  Same tile structure as QKV.
// ---------------------------------------------------------------------------
__global__ __launch_bounds__(256) void out_proj_kernel(
    const float* __restrict__ A, const float* __restrict__ Wo,
    const float* __restrict__ bo, float* __restrict__ out)
{
    __shared__ float As[16][68];
    __shared__ float Bs[16][68];
    const int tid = threadIdx.x;
    const int m0 = blockIdx.x * 64;
    const int n0 = blockIdx.y * 64;
    const int lrow = tid >> 2, lc = tid & 3;
    const int tr = tid >> 4, tc = tid & 15;

    float acc[4][4] = {};
    for (int k0 = 0; k0 < NE; k0 += 16) {
        float4 xa = *reinterpret_cast<const float4*>(&A[(size_t)(m0 + lrow)*NE + k0 + lc*4]);
        float4 wa = *reinterpret_cast<const float4*>(&Wo[(size_t)(n0 + lrow)*NE + k0 + lc*4]);
        __syncthreads();
        As[lc*4+0][lrow] = xa.x; As[lc*4+1][lrow] = xa.y;
        As[lc*4+2][lrow] = xa.z; As[lc*4+3][lrow] = xa.w;
        Bs[lc*4+0][lrow] = wa.x; Bs[lc*4+1][lrow] = wa.y;
        Bs[lc*4+2][lrow] = wa.z; Bs[lc*4+3][lrow] = wa.w;
        __syncthreads();
        #pragma unroll
        for (int kk = 0; kk < 16; ++kk) {
            float4 a4 = *reinterpret_cast<const float4*>(&As[kk][tr*4]);
            float4 b4 = *reinterpret_cast<const float4*>(&Bs[kk][tc*4]);
            float av[4] = {a4.x, a4.y, a4.z, a4.w};
            float bv4[4] = {b4.x, b4.y, b4.z, b4.w};
            #pragma unroll
            for (int i = 0; i < 4; ++i)
                #pragma unroll
                for (int j = 0; j < 4; ++j)
                    acc[i][j] = fmaf(av[i], bv4[j], acc[i][j]);
        }
    }

    float4 bias4 = *reinterpret_cast<const float4*>(&bo[n0 + tc*4]);
    #pragma unroll
    for (int i = 0; i < 4; ++i) {
        int m = m0 + tr*4 + i;
        float4 v4;
        v4.x = acc[i][0] + bias4.x;
        v4.y = acc[i][1] + bias4.y;
        v4.z = acc[i][2] + bias4.z;
        v4.w = acc[i][3] + bias4.w;
        *reinterpret_cast<float4*>(&out[(size_t)m*NE + n0 + tc*4]) = v4;
    }
}

extern "C" void kernel_launch(void* const* d_in, const int* in_sizes, int n_in,
                              void* d_out, int out_size, void* d_ws, size_t ws_size,
                              hipStream_t stream)
{
    const float* x  = (const float*)d_in[0];
    // d_in[1] = attn_mask (tril ones) — causal structure is known; unused.
    const float* Wq = (const float*)d_in[2];
    const float* bq = (const float*)d_in[3];
    const float* Wk = (const float*)d_in[4];
    const float* bk = (const float*)d_in[5];
    const float* Wv = (const float*)d_in[6];
    const float* bv = (const float*)d_in[7];
    const float* Wo = (const float*)d_in[8];
    const float* bo = (const float*)d_in[9];
    float* out = (float*)d_out;

    // Workspace: Q [B,NH,T,D] | K [B,NKV,T,D] | V [B,NKV,T,D] | attn-out [B,T,NE]
    float* Qb = (float*)d_ws;                       // 6,291,456 f
    float* Kb = Qb + (size_t)BSZ*NH*SEQ*HD;         // 3,145,728 f
    float* Vb = Kb + (size_t)BSZ*NKV*SEQ*HD;        // 3,145,728 f
    float* Ab = Vb + (size_t)BSZ*NKV*SEQ*HD;        // 6,291,456 f  (total ~75.5 MB)

    qkv_proj_kernel<<<dim3(MROWS/64, 12), 256, 0, stream>>>(
        x, Wq, bq, Wk, bk, Wv, bv, Qb, Kb, Vb);
    attn_kernel<<<dim3(SEQ/64, NH, BSZ), 256, 0, stream>>>(Qb, Kb, Vb, Ab);
    out_proj_kernel<<<dim3(MROWS/64, NE/64), 256, 0, stream>>>(Ab, Wo, bo, out);
}

// Round 3
// 371.059 us; speedup vs baseline: 2.8568x; 2.8568x over previous
//
#include <hip/hip_runtime.h>
#include <cstdint>
#include <cstddef>

#define NE   384
#define NH   6
#define NKV  3
#define HD   64
#define BSZ  8
#define SEQ  2048
#define MROWS (BSZ*SEQ)

typedef __bf16 bf16x8 __attribute__((ext_vector_type(8)));
typedef __bf16 bf16x4 __attribute__((ext_vector_type(4)));
typedef float  f32x4  __attribute__((ext_vector_type(4)));
typedef unsigned short u16;

// Row-major [rows][64] bf16 LDS tile, row stride 128 B, XOR-swizzled:
// byte_in_row ^= (row&7)<<4  (keeps 16B/8B alignment; kills the 16-way
// conflict of stride-128B column reads — guide §6 G4).
__device__ __forceinline__ bf16x8 ld_frag(const u16* lds, int row, int kk) {
    unsigned off = (unsigned)(row * 128 + ((kk * 2) ^ ((row & 7) << 4)));
    return *reinterpret_cast<const bf16x8*>(reinterpret_cast<const char*>(lds) + off);
}

__device__ __forceinline__ void stage_row4(u16* lds, int row, int c4, float4 v) {
    bf16x4 h;
    h[0] = (__bf16)v.x; h[1] = (__bf16)v.y; h[2] = (__bf16)v.z; h[3] = (__bf16)v.w;
    unsigned off = (unsigned)(row * 128 + ((c4 * 8) ^ ((row & 7) << 4)));
    *reinterpret_cast<bf16x4*>(reinterpret_cast<char*>(lds) + off) = h;
}

// hi/lo bf16 split staging: f = hi + lo with hi = bf16(f), lo = bf16(f - hi)
__device__ __forceinline__ void stage_split(u16* hi, u16* lo, int row, int c4, float4 v) {
    float f[4] = {v.x, v.y, v.z, v.w};
    bf16x4 h, l;
    #pragma unroll
    for (int j = 0; j < 4; ++j) {
        __bf16 a = (__bf16)f[j];
        h[j] = a;
        l[j] = (__bf16)(f[j] - (float)a);
    }
    unsigned off = (unsigned)(row * 128 + ((c4 * 8) ^ ((row & 7) << 4)));
    *reinterpret_cast<bf16x4*>(reinterpret_cast<char*>(hi) + off) = h;
    *reinterpret_cast<bf16x4*>(reinterpret_cast<char*>(lo) + off) = l;
}

#define MFMA(a, b, c) __builtin_amdgcn_mfma_f32_16x16x32_bf16((a), (b), (c), 0, 0, 0)

// ---------------------------------------------------------------------------
// Fused QKV projection, split-bf16 MFMA. Tile 64(M)x64(N), K-chunks of 64.
// 256 threads = 4 waves; wave w owns rows [w*16, w*16+16).
// ---------------------------------------------------------------------------
__global__ __launch_bounds__(256) void qkv_proj_kernel(
    const float* __restrict__ x,
    const float* __restrict__ Wq, const float* __restrict__ bq,
    const float* __restrict__ Wk, const float* __restrict__ bk,
    const float* __restrict__ Wv, const float* __restrict__ bv,
    float* __restrict__ Qb, float* __restrict__ Kb, float* __restrict__ Vb)
{
    __shared__ __align__(16) u16 Ah[64*64], Al[64*64], Wh[64*64], Wl[64*64];
    const int tid = threadIdx.x;
    const int m0 = blockIdx.x * 64;
    const int n0 = blockIdx.y * 64;    // 0..767: Q | K | V columns

    const float* Wrow; const float* bias; float* buf; int nh; int hh;
    if (n0 < 384)      { Wrow = Wq + (size_t)n0*NE;       bias = bq + n0;       buf = Qb; nh = NH;  hh = n0 >> 6; }
    else if (n0 < 576) { Wrow = Wk + (size_t)(n0-384)*NE; bias = bk + (n0-384); buf = Kb; nh = NKV; hh = (n0-384) >> 6; }
    else               { Wrow = Wv + (size_t)(n0-576)*NE; bias = bv + (n0-576); buf = Vb; nh = NKV; hh = (n0-576) >> 6; }

    const int w  = tid >> 6;
    const int l  = tid & 63;
    const int lr = l & 15, lg = l >> 4;

    f32x4 acc[4];
    #pragma unroll
    for (int nt = 0; nt < 4; ++nt) acc[nt] = (f32x4)(0.0f);

    for (int k0 = 0; k0 < NE; k0 += 64) {
        __syncthreads();
        #pragma unroll
        for (int i = 0; i < 4; ++i) {
            int idx = tid + i*256, row = idx >> 4, c4 = idx & 15;
            float4 a4 = *reinterpret_cast<const float4*>(&x[(size_t)(m0+row)*NE + k0 + c4*4]);
            stage_split(Ah, Al, row, c4, a4);
            float4 w4 = *reinterpret_cast<const float4*>(&Wrow[(size_t)row*NE + k0 + c4*4]);
            stage_split(Wh, Wl, row, c4, w4);
        }
        __syncthreads();
        #pragma unroll
        for (int ks = 0; ks < 2; ++ks) {
            bf16x8 ah = ld_frag(Ah, w*16 + lr, ks*32 + lg*8);
            bf16x8 al = ld_frag(Al, w*16 + lr, ks*32 + lg*8);
            #pragma unroll
            for (int nt = 0; nt < 4; ++nt) {
                bf16x8 wh = ld_frag(Wh, nt*16 + lr, ks*32 + lg*8);
                bf16x8 wl = ld_frag(Wl, nt*16 + lr, ks*32 + lg*8);
                acc[nt] = MFMA(ah, wh, acc[nt]);
                acc[nt] = MFMA(al, wh, acc[nt]);
                acc[nt] = MFMA(ah, wl, acc[nt]);
            }
        }
    }

    #pragma unroll
    for (int nt = 0; nt < 4; ++nt) {
        float bv4 = bias[nt*16 + lr];
        #pragma unroll
        for (int r = 0; r < 4; ++r) {
            int m = m0 + w*16 + lg*4 + r;
            int b = m >> 11, t = m & 2047;
            buf[(((size_t)b*nh + hh)*SEQ + t)*HD + nt*16 + lr] = acc[nt][r] + bv4;
        }
    }
}

// ---------------------------------------------------------------------------
// Flash attention, bf16 MFMA. Block = (b, h, 64 q-rows); 4 waves x 16 q-rows.
// Per kv-tile (64 keys): S = QK^T (8 MFMA/wave), online softmax in C-layout,
// P -> per-wave LDS (bf16), O += P V (8 MFMA/wave). V staged transposed.
// Scale 1/sqrt(NE) folded into Q staging.
// ---------------------------------------------------------------------------
__global__ __launch_bounds__(256) void attn_kernel(
    const float* __restrict__ Qb, const float* __restrict__ Kb,
    const float* __restrict__ Vb, float* __restrict__ Ab)
{
    __shared__ __align__(16) u16 Qs[64*64], Ks[64*64], Vt[64*64];
    __shared__ __align__(16) u16 Ps[4][16*64];

    const int tid = threadIdx.x;
    const int w  = tid >> 6;
    const int l  = tid & 63;
    const int lr = l & 15, lg = l >> 4;

    const int qtile = (SEQ/64 - 1) - blockIdx.x;   // heavy tiles first
    const int qt0 = qtile * 64;
    const int h = blockIdx.y, b = blockIdx.z;
    const int kvh = h >> 1;                        // interleaved repeat_kv

    const float* Qbase = Qb + (((size_t)b*NH + h)*SEQ + qt0)*HD;
    const float* Kbase = Kb + ((size_t)b*NKV + kvh)*SEQ*HD;
    const float* Vbase = Vb + ((size_t)b*NKV + kvh)*SEQ*HD;
    const float scale = 0.05103103630798288f;      // 1/sqrt(384)

    // Stage Q once (scaled)
    #pragma unroll
    for (int i = 0; i < 4; ++i) {
        int idx = tid + i*256, row = idx >> 4, c4 = idx & 15;
        float4 q4 = *reinterpret_cast<const float4*>(&Qbase[(size_t)row*HD + c4*4]);
        q4.x *= scale; q4.y *= scale; q4.z *= scale; q4.w *= scale;
        stage_row4(Qs, row, c4, q4);
    }

    f32x4 o[4];
    #pragma unroll
    for (int nt = 0; nt < 4; ++nt) o[nt] = (f32x4)(0.0f);
    float mrun[4], lrun[4];
    #pragma unroll
    for (int r = 0; r < 4; ++r) { mrun[r] = -1e30f; lrun[r] = 0.0f; }

    const int myq0 = qt0 + w*16;
    const int ntiles = qtile + 1;

    for (int jt = 0; jt < ntiles; ++jt) {
        const int j0 = jt * 64;
        __syncthreads();    // prior tile's frag reads complete
        // K tile: row-major [key][d]
        #pragma unroll
        for (int i = 0; i < 4; ++i) {
            int idx = tid + i*256, row = idx >> 4, c4 = idx & 15;
            float4 k4 = *reinterpret_cast<const float4*>(&Kbase[(size_t)(j0+row)*HD + c4*4]);
            stage_row4(Ks, row, c4, k4);
        }
        // V tile transposed: Vt[d][k]. Thread: d = l, k-rows w*16..w*16+15.
        {
            bf16x8 p0, p1;
            #pragma unroll
            for (int s = 0; s < 16; ++s) {
                float f = Vbase[(size_t)(j0 + w*16 + s)*HD + l];
                if (s < 8) p0[s] = (__bf16)f; else p1[s-8] = (__bf16)f;
            }
            unsigned off0 = (unsigned)(l*128 + ((w*32)      ^ ((l & 7) << 4)));
            unsigned off1 = (unsigned)(l*128 + ((w*32 + 16) ^ ((l & 7) << 4)));
            *reinterpret_cast<bf16x8*>(reinterpret_cast<char*>(Vt) + off0) = p0;
            *reinterpret_cast<bf16x8*>(reinterpret_cast<char*>(Vt) + off1) = p1;
        }
        __syncthreads();    // K/V staged

        if (j0 <= myq0 + 15) {   // tile has at least one unmasked key for this wave
            // S = Q K^T
            f32x4 s_acc[4];
            #pragma unroll
            for (int nt = 0; nt < 4; ++nt) s_acc[nt] = (f32x4)(0.0f);
            #pragma unroll
            for (int ks = 0; ks < 2; ++ks) {
                bf16x8 qf = ld_frag(Qs, w*16 + lr, ks*32 + lg*8);
                #pragma unroll
                for (int nt = 0; nt < 4; ++nt) {
                    bf16x8 kf = ld_frag(Ks, nt*16 + lr, ks*32 + lg*8);
                    s_acc[nt] = MFMA(qf, kf, s_acc[nt]);
                }
            }
            // causal mask (only near-diagonal tiles)
            if (j0 + 63 > myq0) {
                #pragma unroll
                for (int nt = 0; nt < 4; ++nt) {
                    int key = j0 + nt*16 + lr;
                    #pragma unroll
                    for (int r = 0; r < 4; ++r) {
                        int q = myq0 + lg*4 + r;
                        if (key > q) s_acc[nt][r] = -1e30f;
                    }
                }
            }
            // online softmax (row stats across 16-lane groups)
            float corr[4];
            #pragma unroll
            for (int r = 0; r < 4; ++r) {
                float mx = fmaxf(fmaxf(s_acc[0][r], s_acc[1][r]),
                                 fmaxf(s_acc[2][r], s_acc[3][r]));
                mx = fmaxf(mx, __shfl_xor(mx, 1));
                mx = fmaxf(mx, __shfl_xor(mx, 2));
                mx = fmaxf(mx, __shfl_xor(mx, 4));
                mx = fmaxf(mx, __shfl_xor(mx, 8));
                float mnew = fmaxf(mrun[r], mx);
                corr[r] = __expf(mrun[r] - mnew);
                mrun[r] = mnew;
                float rs = 0.0f;
                #pragma unroll
                for (int nt = 0; nt < 4; ++nt) {
                    float p = __expf(s_acc[nt][r] - mnew);
                    s_acc[nt][r] = p;
                    rs += p;
                }
                rs += __shfl_xor(rs, 1);
                rs += __shfl_xor(rs, 2);
                rs += __shfl_xor(rs, 4);
                rs += __shfl_xor(rs, 8);
                lrun[r] = lrun[r]*corr[r] + rs;
            }
            // P -> own LDS region (bf16, swizzled); no barrier needed (per-wave)
            u16* P = Ps[w];
            #pragma unroll
            for (int nt = 0; nt < 4; ++nt) {
                #pragma unroll
                for (int r = 0; r < 4; ++r) {
                    int prow = lg*4 + r, pcol = nt*16 + lr;
                    unsigned off = (unsigned)(prow*128 + ((pcol*2) ^ ((prow & 7) << 4)));
                    *reinterpret_cast<__bf16*>(reinterpret_cast<char*>(P) + off) = (__bf16)s_acc[nt][r];
                }
            }
            // rescale O
            #pragma unroll
            for (int nt = 0; nt < 4; ++nt)
                #pragma unroll
                for (int r = 0; r < 4; ++r) o[nt][r] *= corr[r];
            // O += P V
            #pragma unroll
            for (int ks = 0; ks < 2; ++ks) {
                bf16x8 pf = ld_frag(P, lr, ks*32 + lg*8);
                #pragma unroll
                for (int nt = 0; nt < 4; ++nt) {
                    bf16x8 vf = ld_frag(Vt, nt*16 + lr, ks*32 + lg*8);
                    o[nt] = MFMA(pf, vf, o[nt]);
                }
            }
        }
    }

    // normalize + write [B,T,NE]
    #pragma unroll
    for (int r = 0; r < 4; ++r) {
        float inv = 1.0f / lrun[r];
        int t = qt0 + w*16 + lg*4 + r;
        float* dst = &Ab[((size_t)b*SEQ + t)*NE + h*HD];
        #pragma unroll
        for (int nt = 0; nt < 4; ++nt)
            dst[nt*16 + lr] = o[nt][r] * inv;
    }
}

// ---------------------------------------------------------------------------
// Output projection, split-bf16 MFMA. out = A @ Wo.T + bo
// ---------------------------------------------------------------------------
__global__ __launch_bounds__(256) void out_proj_kernel(
    const float* __restrict__ A, const float* __restrict__ Wo,
    const float* __restrict__ bo, float* __restrict__ out)
{
    __shared__ __align__(16) u16 Ah[64*64], Al[64*64], Wh[64*64], Wl[64*64];
    const int tid = threadIdx.x;
    const int m0 = blockIdx.x * 64;
    const int n0 = blockIdx.y * 64;
    const float* Wrow = Wo + (size_t)n0*NE;

    const int w  = tid >> 6;
    const int l  = tid & 63;
    const int lr = l & 15, lg = l >> 4;

    f32x4 acc[4];
    #pragma unroll
    for (int nt = 0; nt < 4; ++nt) acc[nt] = (f32x4)(0.0f);

    for (int k0 = 0; k0 < NE; k0 += 64) {
        __syncthreads();
        #pragma unroll
        for (int i = 0; i < 4; ++i) {
            int idx = tid + i*256, row = idx >> 4, c4 = idx & 15;
            float4 a4 = *reinterpret_cast<const float4*>(&A[(size_t)(m0+row)*NE + k0 + c4*4]);
            stage_split(Ah, Al, row, c4, a4);
            float4 w4 = *reinterpret_cast<const float4*>(&Wrow[(size_t)row*NE + k0 + c4*4]);
            stage_split(Wh, Wl, row, c4, w4);
        }
        __syncthreads();
        #pragma unroll
        for (int ks = 0; ks < 2; ++ks) {
            bf16x8 ah = ld_frag(Ah, w*16 + lr, ks*32 + lg*8);
            bf16x8 al = ld_frag(Al, w*16 + lr, ks*32 + lg*8);
            #pragma unroll
            for (int nt = 0; nt < 4; ++nt) {
                bf16x8 wh = ld_frag(Wh, nt*16 + lr, ks*32 + lg*8);
                bf16x8 wl = ld_frag(Wl, nt*16 + lr, ks*32 + lg*8);
                acc[nt] = MFMA(ah, wh, acc[nt]);
                acc[nt] = MFMA(al, wh, acc[nt]);
                acc[nt] = MFMA(ah, wl, acc[nt]);
            }
        }
    }

    #pragma unroll
    for (int nt = 0; nt < 4; ++nt) {
        float bv4 = bo[n0 + nt*16 + lr];
        #pragma unroll
        for (int r = 0; r < 4; ++r) {
            int m = m0 + w*16 + lg*4 + r;
            out[(size_t)m*NE + n0 + nt*16 + lr] = acc[nt][r] + bv4;
        }
    }
}

extern "C" void kernel_launch(void* const* d_in, const int* in_sizes, int n_in,
                              void* d_out, int out_size, void* d_ws, size_t ws_size,
                              hipStream_t stream)
{
    const float* x  = (const float*)d_in[0];
    // d_in[1] = attn_mask (tril) — causal structure known; unused.
    const float* Wq = (const float*)d_in[2];
    const float* bq = (const float*)d_in[3];
    const float* Wk = (const float*)d_in[4];
    const float* bk = (const float*)d_in[5];
    const float* Wv = (const float*)d_in[6];
    const float* bv = (const float*)d_in[7];
    const float* Wo = (const float*)d_in[8];
    const float* bo = (const float*)d_in[9];
    float* out = (float*)d_out;

    float* Qb = (float*)d_ws;
    float* Kb = Qb + (size_t)BSZ*NH*SEQ*HD;
    float* Vb = Kb + (size_t)BSZ*NKV*SEQ*HD;
    float* Ab = Vb + (size_t)BSZ*NKV*SEQ*HD;

    qkv_proj_kernel<<<dim3(MROWS/64, 12), 256, 0, stream>>>(
        x, Wq, bq, Wk, bk, Wv, bv, Qb, Kb, Vb);
    attn_kernel<<<dim3(SEQ/64, NH, BSZ), 256, 0, stream>>>(Qb, Kb, Vb, Ab);
    out_proj_kernel<<<dim3(MROWS/64, NE/64), 256, 0, stream>>>(Ab, Wo, bo, out);
}

// Round 5
// 286.926 us; speedup vs baseline: 3.6945x; 1.2932x over previous
//
#include <hip/hip_runtime.h>
#include <cstdint>
#include <cstddef>

#define NE   384
#define NH   6
#define NKV  3
#define HD   64
#define BSZ  8
#define SEQ  2048
#define MROWS (BSZ*SEQ)
#define NT_Q (SEQ/64)      // 32 q-tiles

typedef __bf16 bf16x8 __attribute__((ext_vector_type(8)));
typedef __bf16 bf16x4 __attribute__((ext_vector_type(4)));
typedef float  f32x4  __attribute__((ext_vector_type(4)));
typedef unsigned short u16;
typedef u16 u16x8 __attribute__((ext_vector_type(8)));

#define MFMA(a,b,c) __builtin_amdgcn_mfma_f32_16x16x32_bf16((a),(b),(c),0,0,0)
// Q pre-scale: log2(e)/sqrt(384) — softmax done base-2 (v_exp_f32 is 2^x)
#define QSCALE (1.4426950408889634f * 0.05103103630798288f)

// ---- swizzled LDS tile helpers: row-major, row stride 128 B (64 bf16),
// ---- byte-in-row ^= (row&7)<<4  (conflict-free b128 column reads; G4/T2)
__device__ __forceinline__ bf16x8 ld_frag(const u16* lds, int row, int kk) {
    unsigned off = (unsigned)(row*128 + ((kk*2) ^ ((row&7)<<4)));
    return *reinterpret_cast<const bf16x8*>(reinterpret_cast<const char*>(lds) + off);
}
__device__ __forceinline__ void st_frag(u16* lds, int row, int kk, u16x8 v) {
    unsigned off = (unsigned)(row*128 + ((kk*2) ^ ((row&7)<<4)));
    *reinterpret_cast<u16x8*>(reinterpret_cast<char*>(lds) + off) = v;
}

// ---------------------------------------------------------------------------
// Prep: split fp32 -> (hi, lo) bf16 for x and all weights. Runs once per call.
// ---------------------------------------------------------------------------
__global__ __launch_bounds__(256) void prep_kernel(
    const float* __restrict__ x,  const float* __restrict__ Wq,
    const float* __restrict__ Wk, const float* __restrict__ Wv,
    const float* __restrict__ Wo,
    __bf16* xh, __bf16* xl, __bf16* wqh, __bf16* wql,
    __bf16* wkh, __bf16* wkl, __bf16* wvh, __bf16* wvl,
    __bf16* woh, __bf16* wol)
{
    const float* src; __bf16 *dh, *dl; int n4;
    switch (blockIdx.y) {
        case 0:  src = x;  dh = xh;  dl = xl;  n4 = MROWS*NE/4; break;
        case 1:  src = Wq; dh = wqh; dl = wql; n4 = 384*NE/4;   break;
        case 2:  src = Wk; dh = wkh; dl = wkl; n4 = 192*NE/4;   break;
        case 3:  src = Wv; dh = wvh; dl = wvl; n4 = 192*NE/4;   break;
        default: src = Wo; dh = woh; dl = wol; n4 = 384*NE/4;   break;
    }
    for (int i = blockIdx.x*256 + threadIdx.x; i < n4; i += gridDim.x*256) {
        float4 v = reinterpret_cast<const float4*>(src)[i];
        float f[4] = {v.x, v.y, v.z, v.w};
        bf16x4 h, l;
        #pragma unroll
        for (int j = 0; j < 4; ++j) {
            __bf16 a = (__bf16)f[j];
            h[j] = a;
            l[j] = (__bf16)(f[j] - (float)a);
        }
        reinterpret_cast<bf16x4*>(dh)[i] = h;
        reinterpret_cast<bf16x4*>(dl)[i] = l;
    }
}

// ---------------------------------------------------------------------------
// QKV projection from bf16 hi/lo inputs. BM=64, BN=192, BK=64, 4 waves.
// Wave w owns all 64 rows x cols [w*48, w*48+48) (3 MFMA per LDS read).
// 3-term split: ah*wh + al*wh + ah*wl.
// Q written pre-scaled bf16; K/V written bf16.
// ---------------------------------------------------------------------------
__global__ __launch_bounds__(256) void qkv_proj_kernel(
    const __bf16* __restrict__ xh, const __bf16* __restrict__ xl,
    const __bf16* __restrict__ wqh, const __bf16* __restrict__ wql,
    const __bf16* __restrict__ wkh, const __bf16* __restrict__ wkl,
    const __bf16* __restrict__ wvh, const __bf16* __restrict__ wvl,
    const float* __restrict__ bq, const float* __restrict__ bk,
    const float* __restrict__ bv,
    __bf16* __restrict__ Qb, __bf16* __restrict__ Kb, __bf16* __restrict__ Vb)
{
    __shared__ __align__(16) u16 Ah_s[64*64], Al_s[64*64];
    __shared__ __align__(16) u16 Wh_s[192*64], Wl_s[192*64];   // total 64 KB

    const int tid = threadIdx.x;
    const int m0 = blockIdx.x * 64;
    const int w  = tid >> 6, l = tid & 63;
    const int lr = l & 15, lg = l >> 4;

    const __bf16 *Wh, *Wl; const float* bias; int outsel, colbase;
    if (blockIdx.y == 0)      { Wh = wqh;          Wl = wql;          bias = bq; outsel = 0; colbase = 0;   }
    else if (blockIdx.y == 1) { Wh = wqh + 192*NE; Wl = wql + 192*NE; bias = bq; outsel = 0; colbase = 192; }
    else if (blockIdx.y == 2) { Wh = wkh;          Wl = wkl;          bias = bk; outsel = 1; colbase = 0;   }
    else                      { Wh = wvh;          Wl = wvl;          bias = bv; outsel = 2; colbase = 0;   }

    f32x4 acc[4][3];
    #pragma unroll
    for (int mt = 0; mt < 4; ++mt)
        #pragma unroll
        for (int nt = 0; nt < 3; ++nt) acc[mt][nt] = (f32x4)(0.0f);

    for (int k0 = 0; k0 < NE; k0 += 64) {
        __syncthreads();
        #pragma unroll
        for (int i = 0; i < 2; ++i) {   // A: 64 rows x 8 chunks = 512
            int c = tid + i*256, row = c >> 3, c8 = c & 7;
            st_frag(Ah_s, row, c8*8, *reinterpret_cast<const u16x8*>(&xh[(size_t)(m0+row)*NE + k0 + c8*8]));
            st_frag(Al_s, row, c8*8, *reinterpret_cast<const u16x8*>(&xl[(size_t)(m0+row)*NE + k0 + c8*8]));
        }
        #pragma unroll
        for (int i = 0; i < 6; ++i) {   // W: 192 rows x 8 chunks = 1536 (BUGFIX: was 3 -> rows 96..191 never staged)
            int c = tid + i*256, row = c >> 3, c8 = c & 7;
            st_frag(Wh_s, row, c8*8, *reinterpret_cast<const u16x8*>(&Wh[(size_t)row*NE + k0 + c8*8]));
            st_frag(Wl_s, row, c8*8, *reinterpret_cast<const u16x8*>(&Wl[(size_t)row*NE + k0 + c8*8]));
        }
        __syncthreads();
        #pragma unroll
        for (int ks = 0; ks < 2; ++ks) {
            bf16x8 ah[4], al[4];
            #pragma unroll
            for (int mt = 0; mt < 4; ++mt) {
                ah[mt] = ld_frag(Ah_s, mt*16 + lr, ks*32 + lg*8);
                al[mt] = ld_frag(Al_s, mt*16 + lr, ks*32 + lg*8);
            }
            #pragma unroll
            for (int nt = 0; nt < 3; ++nt) {
                bf16x8 whf = ld_frag(Wh_s, w*48 + nt*16 + lr, ks*32 + lg*8);
                bf16x8 wlf = ld_frag(Wl_s, w*48 + nt*16 + lr, ks*32 + lg*8);
                #pragma unroll
                for (int mt = 0; mt < 4; ++mt) {
                    acc[mt][nt] = MFMA(ah[mt], whf, acc[mt][nt]);
                    acc[mt][nt] = MFMA(al[mt], whf, acc[mt][nt]);
                    acc[mt][nt] = MFMA(ah[mt], wlf, acc[mt][nt]);
                }
            }
        }
    }

    #pragma unroll
    for (int nt = 0; nt < 3; ++nt) {
        int colt = colbase + w*48 + nt*16 + lr;   // col within this projection
        float bb = bias[colt];
        int hh = colt >> 6, dd = colt & 63;
        #pragma unroll
        for (int mt = 0; mt < 4; ++mt) {
            #pragma unroll
            for (int r = 0; r < 4; ++r) {
                int m = m0 + mt*16 + lg*4 + r;
                int b8 = m >> 11, t = m & 2047;
                float val = acc[mt][nt][r] + bb;
                if (outsel == 0)
                    Qb[(((size_t)b8*NH + hh)*SEQ + t)*HD + dd] = (__bf16)(val * QSCALE);
                else if (outsel == 1)
                    Kb[(((size_t)b8*NKV + hh)*SEQ + t)*HD + dd] = (__bf16)val;
                else
                    Vb[(((size_t)b8*NKV + hh)*SEQ + t)*HD + dd] = (__bf16)val;
            }
        }
    }
}

// ---------------------------------------------------------------------------
// Flash attention, bf16 MFMA, base-2 online softmax (Q pre-scaled).
// Block = (pair p, h, b); processes q-tiles p and 31-p sequentially ->
// uniform 33 kv-iterations per block (kills the causal tail).
// K/V double-buffered in LDS, prefetch loads issued before compute,
// one barrier per kv-tile. Output written as hi/lo bf16.
// ---------------------------------------------------------------------------
__global__ __launch_bounds__(256) void attn_kernel(
    const __bf16* __restrict__ Qb, const __bf16* __restrict__ Kb,
    const __bf16* __restrict__ Vb,
    __bf16* __restrict__ Aho, __bf16* __restrict__ Alo)
{
    __shared__ __align__(16) u16 Qs[64*64];
    __shared__ __align__(16) u16 Kbuf[2][64*64];
    __shared__ __align__(16) u16 Vbuf[2][64*64];
    __shared__ __align__(16) u16 Ps[4][16*64];     // total 48 KB

    const int tid = threadIdx.x;
    const int w  = tid >> 6, l = tid & 63;
    const int lr = l & 15, lg = l >> 4;
    const int p = blockIdx.x, h = blockIdx.y, b = blockIdx.z;
    const int kvh = h >> 1;

    const __bf16* Kbase = Kb + ((size_t)b*NKV + kvh)*SEQ*HD;
    const __bf16* Vbase = Vb + ((size_t)b*NKV + kvh)*SEQ*HD;

    // V-transpose staging coords (fixed per thread)
    const int vd0 = 2*(tid & 31), vkb = (tid >> 5)*8;

    for (int pass = 0; pass < 2; ++pass) {
        const int qtile = pass ? (NT_Q-1-p) : p;
        const int qt0 = qtile * 64;
        const __bf16* Qbase = Qb + (((size_t)b*NH + h)*SEQ + qt0)*HD;

        // stage Q (already scaled by log2e/sqrt(NE))
        #pragma unroll
        for (int i = 0; i < 2; ++i) {
            int c = tid + i*256, row = c >> 3, c8 = c & 7;
            st_frag(Qs, row, c8*8, *reinterpret_cast<const u16x8*>(&Qbase[(size_t)row*HD + c8*8]));
        }
        // stage K/V tile 0 -> buf 0
        #pragma unroll
        for (int i = 0; i < 2; ++i) {
            int c = tid + i*256, row = c >> 3, c8 = c & 7;
            st_frag(Kbuf[0], row, c8*8, *reinterpret_cast<const u16x8*>(&Kbase[(size_t)row*HD + c8*8]));
        }
        {
            unsigned vp[8];
            #pragma unroll
            for (int j = 0; j < 8; ++j)
                vp[j] = *reinterpret_cast<const unsigned*>(&Vbase[(size_t)(vkb+j)*HD + vd0]);
            u16x8 r0, r1;
            #pragma unroll
            for (int j = 0; j < 8; ++j) { r0[j] = (u16)(vp[j] & 0xffffu); r1[j] = (u16)(vp[j] >> 16); }
            st_frag(Vbuf[0], vd0,   vkb, r0);
            st_frag(Vbuf[0], vd0+1, vkb, r1);
        }
        __syncthreads();

        f32x4 o[4];
        #pragma unroll
        for (int nt = 0; nt < 4; ++nt) o[nt] = (f32x4)(0.0f);
        float mrun[4], lrun[4];
        #pragma unroll
        for (int r = 0; r < 4; ++r) { mrun[r] = -1e30f; lrun[r] = 0.0f; }
        const int myq0 = qt0 + w*16;

        int cur = 0;
        for (int jt = 0; jt <= qtile; ++jt) {
            const bool pre = (jt < qtile);
            u16x8 kpre0, kpre1; unsigned vp[8];
            if (pre) {   // issue next-tile loads (latency hides under compute)
                const int jn = (jt+1)*64;
                { int c = tid,     row = c >> 3, c8 = c & 7;
                  kpre0 = *reinterpret_cast<const u16x8*>(&Kbase[(size_t)(jn+row)*HD + c8*8]); }
                { int c = tid+256, row = c >> 3, c8 = c & 7;
                  kpre1 = *reinterpret_cast<const u16x8*>(&Kbase[(size_t)(jn+row)*HD + c8*8]); }
                #pragma unroll
                for (int j = 0; j < 8; ++j)
                    vp[j] = *reinterpret_cast<const unsigned*>(&Vbase[(size_t)(jn+vkb+j)*HD + vd0]);
            }

            const u16* Kc = Kbuf[cur];
            const u16* Vc = Vbuf[cur];

            // S = Q K^T (pre-scaled)
            f32x4 s_acc[4];
            #pragma unroll
            for (int nt = 0; nt < 4; ++nt) s_acc[nt] = (f32x4)(0.0f);
            #pragma unroll
            for (int ks = 0; ks < 2; ++ks) {
                bf16x8 qf = ld_frag(Qs, w*16 + lr, ks*32 + lg*8);
                #pragma unroll
                for (int nt = 0; nt < 4; ++nt)
                    s_acc[nt] = MFMA(qf, ld_frag(Kc, nt*16 + lr, ks*32 + lg*8), s_acc[nt]);
            }
            // causal mask — only the diagonal tile
            if (jt == qtile) {
                const int j0 = jt*64;
                #pragma unroll
                for (int nt = 0; nt < 4; ++nt) {
                    int key = j0 + nt*16 + lr;
                    #pragma unroll
                    for (int r = 0; r < 4; ++r)
                        if (key > myq0 + lg*4 + r) s_acc[nt][r] = -1e30f;
                }
            }
            // online softmax, base 2
            float corr[4];
            #pragma unroll
            for (int r = 0; r < 4; ++r) {
                float mx = fmaxf(fmaxf(s_acc[0][r], s_acc[1][r]),
                                 fmaxf(s_acc[2][r], s_acc[3][r]));
                mx = fmaxf(mx, __shfl_xor(mx, 1));
                mx = fmaxf(mx, __shfl_xor(mx, 2));
                mx = fmaxf(mx, __shfl_xor(mx, 4));
                mx = fmaxf(mx, __shfl_xor(mx, 8));
                float mnew = fmaxf(mrun[r], mx);
                corr[r] = exp2f(mrun[r] - mnew);
                mrun[r] = mnew;
                float rs = 0.0f;
                #pragma unroll
                for (int nt = 0; nt < 4; ++nt) {
                    float pv = exp2f(s_acc[nt][r] - mnew);
                    s_acc[nt][r] = pv;
                    rs += pv;
                }
                rs += __shfl_xor(rs, 1);
                rs += __shfl_xor(rs, 2);
                rs += __shfl_xor(rs, 4);
                rs += __shfl_xor(rs, 8);
                lrun[r] = lrun[r]*corr[r] + rs;
            }
            // P -> per-wave LDS (no barrier: private region)
            u16* P = Ps[w];
            #pragma unroll
            for (int nt = 0; nt < 4; ++nt)
                #pragma unroll
                for (int r = 0; r < 4; ++r) {
                    int prow = lg*4 + r, pcol = nt*16 + lr;
                    unsigned off = (unsigned)(prow*128 + ((pcol*2) ^ ((prow&7)<<4)));
                    *reinterpret_cast<__bf16*>(reinterpret_cast<char*>(P) + off) = (__bf16)s_acc[nt][r];
                }
            #pragma unroll
            for (int nt = 0; nt < 4; ++nt)
                #pragma unroll
                for (int r = 0; r < 4; ++r) o[nt][r] *= corr[r];
            // O += P V
            #pragma unroll
            for (int ks = 0; ks < 2; ++ks) {
                bf16x8 pf = ld_frag(P, lr, ks*32 + lg*8);
                #pragma unroll
                for (int nt = 0; nt < 4; ++nt)
                    o[nt] = MFMA(pf, ld_frag(Vc, nt*16 + lr, ks*32 + lg*8), o[nt]);
            }

            if (pre) {   // drain prefetch into the other buffer
                u16* Kd = Kbuf[cur ^ 1];
                u16* Vd = Vbuf[cur ^ 1];
                { int c = tid,     row = c >> 3, c8 = c & 7; st_frag(Kd, row, c8*8, kpre0); }
                { int c = tid+256, row = c >> 3, c8 = c & 7; st_frag(Kd, row, c8*8, kpre1); }
                u16x8 r0, r1;
                #pragma unroll
                for (int j = 0; j < 8; ++j) { r0[j] = (u16)(vp[j] & 0xffffu); r1[j] = (u16)(vp[j] >> 16); }
                st_frag(Vd, vd0,   vkb, r0);
                st_frag(Vd, vd0+1, vkb, r1);
            }
            __syncthreads();
            cur ^= 1;
        }

        // epilogue: A = O/l, written as hi/lo bf16 [B,T,NE]
        #pragma unroll
        for (int r = 0; r < 4; ++r) {
            float inv = 1.0f / lrun[r];
            int t = qt0 + w*16 + lg*4 + r;
            size_t base = ((size_t)b*SEQ + t)*NE + h*HD;
            #pragma unroll
            for (int nt = 0; nt < 4; ++nt) {
                float v = o[nt][r] * inv;
                __bf16 hi = (__bf16)v;
                Aho[base + nt*16 + lr] = hi;
                Alo[base + nt*16 + lr] = (__bf16)(v - (float)hi);
            }
        }
    }
}

// ---------------------------------------------------------------------------
// Output projection from bf16 hi/lo A and Wo. Same structure as QKV.
// ---------------------------------------------------------------------------
__global__ __launch_bounds__(256) void out_proj_kernel(
    const __bf16* __restrict__ Ahi, const __bf16* __restrict__ Alo,
    const __bf16* __restrict__ woh, const __bf16* __restrict__ wol,
    const float* __restrict__ bo, float* __restrict__ out)
{
    __shared__ __align__(16) u16 Ah_s[64*64], Al_s[64*64];
    __shared__ __align__(16) u16 Wh_s[192*64], Wl_s[192*64];

    const int tid = threadIdx.x;
    const int m0 = blockIdx.x * 64;
    const int n0 = blockIdx.y * 192;
    const int w  = tid >> 6, l = tid & 63;
    const int lr = l & 15, lg = l >> 4;
    const __bf16* Wh = woh + (size_t)n0*NE;
    const __bf16* Wl = wol + (size_t)n0*NE;

    f32x4 acc[4][3];
    #pragma unroll
    for (int mt = 0; mt < 4; ++mt)
        #pragma unroll
        for (int nt = 0; nt < 3; ++nt) acc[mt][nt] = (f32x4)(0.0f);

    for (int k0 = 0; k0 < NE; k0 += 64) {
        __syncthreads();
        #pragma unroll
        for (int i = 0; i < 2; ++i) {
            int c = tid + i*256, row = c >> 3, c8 = c & 7;
            st_frag(Ah_s, row, c8*8, *reinterpret_cast<const u16x8*>(&Ahi[(size_t)(m0+row)*NE + k0 + c8*8]));
            st_frag(Al_s, row, c8*8, *reinterpret_cast<const u16x8*>(&Alo[(size_t)(m0+row)*NE + k0 + c8*8]));
        }
        #pragma unroll
        for (int i = 0; i < 6; ++i) {   // 192 rows x 8 chunks = 1536 (BUGFIX: was 3)
            int c = tid + i*256, row = c >> 3, c8 = c & 7;
            st_frag(Wh_s, row, c8*8, *reinterpret_cast<const u16x8*>(&Wh[(size_t)row*NE + k0 + c8*8]));
            st_frag(Wl_s, row, c8*8, *reinterpret_cast<const u16x8*>(&Wl[(size_t)row*NE + k0 + c8*8]));
        }
        __syncthreads();
        #pragma unroll
        for (int ks = 0; ks < 2; ++ks) {
            bf16x8 ah[4], al[4];
            #pragma unroll
            for (int mt = 0; mt < 4; ++mt) {
                ah[mt] = ld_frag(Ah_s, mt*16 + lr, ks*32 + lg*8);
                al[mt] = ld_frag(Al_s, mt*16 + lr, ks*32 + lg*8);
            }
            #pragma unroll
            for (int nt = 0; nt < 3; ++nt) {
                bf16x8 whf = ld_frag(Wh_s, w*48 + nt*16 + lr, ks*32 + lg*8);
                bf16x8 wlf = ld_frag(Wl_s, w*48 + nt*16 + lr, ks*32 + lg*8);
                #pragma unroll
                for (int mt = 0; mt < 4; ++mt) {
                    acc[mt][nt] = MFMA(ah[mt], whf, acc[mt][nt]);
                    acc[mt][nt] = MFMA(al[mt], whf, acc[mt][nt]);
                    acc[mt][nt] = MFMA(ah[mt], wlf, acc[mt][nt]);
                }
            }
        }
    }

    #pragma unroll
    for (int nt = 0; nt < 3; ++nt) {
        int col = n0 + w*48 + nt*16 + lr;
        float bb = bo[col];
        #pragma unroll
        for (int mt = 0; mt < 4; ++mt)
            #pragma unroll
            for (int r = 0; r < 4; ++r) {
                int m = m0 + mt*16 + lg*4 + r;
                out[(size_t)m*NE + col] = acc[mt][nt][r] + bb;
            }
    }
}

extern "C" void kernel_launch(void* const* d_in, const int* in_sizes, int n_in,
                              void* d_out, int out_size, void* d_ws, size_t ws_size,
                              hipStream_t stream)
{
    const float* x  = (const float*)d_in[0];
    // d_in[1] = attn_mask (tril) — causal structure known; unused.
    const float* Wq = (const float*)d_in[2];
    const float* bq = (const float*)d_in[3];
    const float* Wk = (const float*)d_in[4];
    const float* bk = (const float*)d_in[5];
    const float* Wv = (const float*)d_in[6];
    const float* bv = (const float*)d_in[7];
    const float* Wo = (const float*)d_in[8];
    const float* bo = (const float*)d_in[9];
    float* out = (float*)d_out;

    // ws layout (bf16 elements)
    __bf16* xh  = (__bf16*)d_ws;
    __bf16* xl  = xh  + (size_t)MROWS*NE;       // 6,291,456
    __bf16* wqh = xl  + (size_t)MROWS*NE;
    __bf16* wql = wqh + 384*NE;
    __bf16* wkh = wql + 384*NE;
    __bf16* wkl = wkh + 192*NE;
    __bf16* wvh = wkl + 192*NE;
    __bf16* wvl = wvh + 192*NE;
    __bf16* woh = wvl + 192*NE;
    __bf16* wol = woh + 384*NE;
    __bf16* Qb  = wol + 384*NE;                 // [B,NH,T,D] bf16, pre-scaled
    __bf16* Kb  = Qb + (size_t)BSZ*NH*SEQ*HD;
    __bf16* Vb  = Kb + (size_t)BSZ*NKV*SEQ*HD;
    // attn output aliases xh/xl (dead after qkv_proj)
    __bf16* Aho = xh;
    __bf16* Alo = xl;

    prep_kernel<<<dim3(512, 5), 256, 0, stream>>>(
        x, Wq, Wk, Wv, Wo, xh, xl, wqh, wql, wkh, wkl, wvh, wvl, woh, wol);
    qkv_proj_kernel<<<dim3(MROWS/64, 4), 256, 0, stream>>>(
        xh, xl, wqh, wql, wkh, wkl, wvh, wvl, bq, bk, bv, Qb, Kb, Vb);
    attn_kernel<<<dim3(NT_Q/2, NH, BSZ), 256, 0, stream>>>(Qb, Kb, Vb, Aho, Alo);
    out_proj_kernel<<<dim3(MROWS/64, 2), 256, 0, stream>>>(Aho, Alo, woh, wol, bo, out);
}

// Round 6
// 210.106 us; speedup vs baseline: 5.0453x; 1.3656x over previous
//
#include <hip/hip_runtime.h>
#include <cstdint>
#include <cstddef>

#define NE   384
#define NH   6
#define NKV  3
#define HD   64
#define BSZ  8
#define SEQ  2048
#define MROWS (BSZ*SEQ)
#define NT_Q (SEQ/64)      // 32 q-tiles

typedef __bf16 bf16x8 __attribute__((ext_vector_type(8)));
typedef __bf16 bf16x4 __attribute__((ext_vector_type(4)));
typedef float  f32x4  __attribute__((ext_vector_type(4)));
typedef unsigned short u16;
typedef u16 u16x8 __attribute__((ext_vector_type(8)));
typedef u16 u16x4 __attribute__((ext_vector_type(4)));

#define MFMA(a,b,c) __builtin_amdgcn_mfma_f32_16x16x32_bf16((a),(b),(c),0,0,0)
// Q pre-scale: log2(e)/sqrt(384) — softmax done base-2 (v_exp_f32 is 2^x)
#define QSCALE (1.4426950408889634f * 0.05103103630798288f)

// ---- swizzled LDS tiles: row-major, row stride 128 B (64 bf16),
// ---- byte-in-row ^= (row&7)<<4  (conflict-free b128 column reads; G4/T2)
__device__ __forceinline__ bf16x8 ld_frag(const u16* lds, int row, int kk) {
    unsigned off = (unsigned)(row*128 + ((kk*2) ^ ((row&7)<<4)));
    return *reinterpret_cast<const bf16x8*>(reinterpret_cast<const char*>(lds) + off);
}
__device__ __forceinline__ void st_frag(u16* lds, int row, int kk, u16x8 v) {
    unsigned off = (unsigned)(row*128 + ((kk*2) ^ ((row&7)<<4)));
    *reinterpret_cast<u16x8*>(reinterpret_cast<char*>(lds) + off) = v;
}
// V tile: staged as d-pairs (rows always even+odd) -> swizzle on (row>>1)&7
// so staging-write phases hit 8 distinct slots (round-5's 1.6e6 conflicts fix)
__device__ __forceinline__ bf16x8 ld_fragV(const u16* lds, int row, int kk) {
    unsigned off = (unsigned)(row*128 + ((kk*2) ^ (((row>>1)&7)<<4)));
    return *reinterpret_cast<const bf16x8*>(reinterpret_cast<const char*>(lds) + off);
}
__device__ __forceinline__ void st_fragV(u16* lds, int row, int kk, u16x8 v) {
    unsigned off = (unsigned)(row*128 + ((kk*2) ^ (((row>>1)&7)<<4)));
    *reinterpret_cast<u16x8*>(reinterpret_cast<char*>(lds) + off) = v;
}
// packed b64 store into a (row&7)-swizzled tile (8B offsets stay 8-aligned)
__device__ __forceinline__ void st_b64(u16* lds, int row, int col, u16x4 v) {
    unsigned off = (unsigned)(row*128 + ((col*2) ^ ((row&7)<<4)));
    *reinterpret_cast<u16x4*>(reinterpret_cast<char*>(lds) + off) = v;
}
__device__ __forceinline__ u16x4 pack4(f32x4 v) {
    bf16x4 h;
    h[0] = (__bf16)v[0]; h[1] = (__bf16)v[1]; h[2] = (__bf16)v[2]; h[3] = (__bf16)v[3];
    return *reinterpret_cast<u16x4*>(&h);
}

// ---------------------------------------------------------------------------
// Prep: fp32 -> bf16 for x and all weights (plain bf16; hi/lo dropped —
// round-3/5 margin 6.5x and attention path dominates rounding).
// ---------------------------------------------------------------------------
__global__ __launch_bounds__(256) void prep_kernel(
    const float* __restrict__ x,  const float* __restrict__ Wq,
    const float* __restrict__ Wk, const float* __restrict__ Wv,
    const float* __restrict__ Wo,
    __bf16* xb, __bf16* wqb, __bf16* wkb, __bf16* wvb, __bf16* wob)
{
    const float* src; __bf16* dst; int n4;
    switch (blockIdx.y) {
        case 0:  src = x;  dst = xb;  n4 = MROWS*NE/4; break;
        case 1:  src = Wq; dst = wqb; n4 = 384*NE/4;   break;
        case 2:  src = Wk; dst = wkb; n4 = 192*NE/4;   break;
        case 3:  src = Wv; dst = wvb; n4 = 192*NE/4;   break;
        default: src = Wo; dst = wob; n4 = 384*NE/4;   break;
    }
    for (int i = blockIdx.x*256 + threadIdx.x; i < n4; i += gridDim.x*256) {
        float4 v = reinterpret_cast<const float4*>(src)[i];
        bf16x4 h;
        h[0] = (__bf16)v.x; h[1] = (__bf16)v.y; h[2] = (__bf16)v.z; h[3] = (__bf16)v.w;
        reinterpret_cast<bf16x4*>(dst)[i] = h;
    }
}

// ---------------------------------------------------------------------------
// QKV projection, plain bf16. BM=64, BN=192, BK=64, 4 waves; wave w owns
// cols [w*48, w*48+48). LDS 32 KB -> 5 blocks/CU.
// ---------------------------------------------------------------------------
__global__ __launch_bounds__(256) void qkv_proj_kernel(
    const __bf16* __restrict__ xb,
    const __bf16* __restrict__ wqb, const __bf16* __restrict__ wkb,
    const __bf16* __restrict__ wvb,
    const float* __restrict__ bq, const float* __restrict__ bk,
    const float* __restrict__ bv,
    __bf16* __restrict__ Qb, __bf16* __restrict__ Kb, __bf16* __restrict__ Vb)
{
    __shared__ __align__(16) u16 A_s[64*64], W_s[192*64];   // 8 + 24 KB

    const int tid = threadIdx.x;
    const int m0 = blockIdx.x * 64;
    const int w  = tid >> 6, l = tid & 63;
    const int lr = l & 15, lg = l >> 4;

    const __bf16* W; const float* bias; int outsel, colbase;
    if (blockIdx.y == 0)      { W = wqb;          bias = bq; outsel = 0; colbase = 0;   }
    else if (blockIdx.y == 1) { W = wqb + 192*NE; bias = bq; outsel = 0; colbase = 192; }
    else if (blockIdx.y == 2) { W = wkb;          bias = bk; outsel = 1; colbase = 0;   }
    else                      { W = wvb;          bias = bv; outsel = 2; colbase = 0;   }

    f32x4 acc[4][3];
    #pragma unroll
    for (int mt = 0; mt < 4; ++mt)
        #pragma unroll
        for (int nt = 0; nt < 3; ++nt) acc[mt][nt] = (f32x4)(0.0f);

    for (int k0 = 0; k0 < NE; k0 += 64) {
        __syncthreads();
        #pragma unroll
        for (int i = 0; i < 2; ++i) {   // A: 64 rows x 8 chunks
            int c = tid + i*256, row = c >> 3, c8 = c & 7;
            st_frag(A_s, row, c8*8, *reinterpret_cast<const u16x8*>(&xb[(size_t)(m0+row)*NE + k0 + c8*8]));
        }
        #pragma unroll
        for (int i = 0; i < 6; ++i) {   // W: 192 rows x 8 chunks
            int c = tid + i*256, row = c >> 3, c8 = c & 7;
            st_frag(W_s, row, c8*8, *reinterpret_cast<const u16x8*>(&W[(size_t)row*NE + k0 + c8*8]));
        }
        __syncthreads();
        #pragma unroll
        for (int ks = 0; ks < 2; ++ks) {
            bf16x8 ah[4];
            #pragma unroll
            for (int mt = 0; mt < 4; ++mt)
                ah[mt] = ld_frag(A_s, mt*16 + lr, ks*32 + lg*8);
            #pragma unroll
            for (int nt = 0; nt < 3; ++nt) {
                bf16x8 wf = ld_frag(W_s, w*48 + nt*16 + lr, ks*32 + lg*8);
                #pragma unroll
                for (int mt = 0; mt < 4; ++mt)
                    acc[mt][nt] = MFMA(ah[mt], wf, acc[mt][nt]);
            }
        }
    }

    #pragma unroll
    for (int nt = 0; nt < 3; ++nt) {
        int colt = colbase + w*48 + nt*16 + lr;
        float bb = bias[colt];
        int hh = colt >> 6, dd = colt & 63;
        #pragma unroll
        for (int mt = 0; mt < 4; ++mt) {
            #pragma unroll
            for (int r = 0; r < 4; ++r) {
                int m = m0 + mt*16 + lg*4 + r;
                int b8 = m >> 11, t = m & 2047;
                float val = acc[mt][nt][r] + bb;
                if (outsel == 0)
                    Qb[(((size_t)b8*NH + hh)*SEQ + t)*HD + dd] = (__bf16)(val * QSCALE);
                else if (outsel == 1)
                    Kb[(((size_t)b8*NKV + hh)*SEQ + t)*HD + dd] = (__bf16)val;
                else
                    Vb[(((size_t)b8*NKV + hh)*SEQ + t)*HD + dd] = (__bf16)val;
            }
        }
    }
}

// ---------------------------------------------------------------------------
// Flash attention, SWAPPED-OPERAND form (reduction axis lane-local, T12):
//   S^T = mfma(K, Q)  -> lane holds q = lane&15, keys nt*16 + lg*4 + r
//   softmax: in-lane over 16 keys + 2 shfl_xor (16,32); m/l are SCALARS
//   P -> per-wave LDS via 4 packed ds_write_b64 (was 16 scalar b16)
//   O^T = mfma(V, P)  -> same fragment reads; corr/lrun rescale lane-local
// Block = (pair p, h, b): q-tiles p and 31-p -> uniform 33 kv-iterations.
// K/V double-buffered, prefetch-issued before compute, 1 barrier/iter.
// ---------------------------------------------------------------------------
__global__ __launch_bounds__(256) void attn_kernel(
    const __bf16* __restrict__ Qb, const __bf16* __restrict__ Kb,
    const __bf16* __restrict__ Vb, __bf16* __restrict__ Ab)
{
    __shared__ __align__(16) u16 Qs[64*64];
    __shared__ __align__(16) u16 Kbuf[2][64*64];
    __shared__ __align__(16) u16 Vbuf[2][64*64];
    __shared__ __align__(16) u16 Ps[4][16*64];     // 48 KB total

    const int tid = threadIdx.x;
    const int w  = tid >> 6, l = tid & 63;
    const int lr = l & 15, lg = l >> 4;
    const int p = blockIdx.x, h = blockIdx.y, b = blockIdx.z;
    const int kvh = h >> 1;                        // interleaved repeat_kv

    const __bf16* Kbase = Kb + ((size_t)b*NKV + kvh)*SEQ*HD;
    const __bf16* Vbase = Vb + ((size_t)b*NKV + kvh)*SEQ*HD;

    // V-transpose staging coords (d-pair per thread, key-chunk per tid>>5)
    const int vd0 = 2*(tid & 31), vkb = (tid >> 5)*8;

    for (int pass = 0; pass < 2; ++pass) {
        const int qtile = pass ? (NT_Q-1-p) : p;
        const int qt0 = qtile * 64;
        const __bf16* Qbase = Qb + (((size_t)b*NH + h)*SEQ + qt0)*HD;

        #pragma unroll
        for (int i = 0; i < 2; ++i) {
            int c = tid + i*256, row = c >> 3, c8 = c & 7;
            st_frag(Qs, row, c8*8, *reinterpret_cast<const u16x8*>(&Qbase[(size_t)row*HD + c8*8]));
        }
        #pragma unroll
        for (int i = 0; i < 2; ++i) {
            int c = tid + i*256, row = c >> 3, c8 = c & 7;
            st_frag(Kbuf[0], row, c8*8, *reinterpret_cast<const u16x8*>(&Kbase[(size_t)row*HD + c8*8]));
        }
        {
            unsigned vp[8];
            #pragma unroll
            for (int j = 0; j < 8; ++j)
                vp[j] = *reinterpret_cast<const unsigned*>(&Vbase[(size_t)(vkb+j)*HD + vd0]);
            u16x8 r0, r1;
            #pragma unroll
            for (int j = 0; j < 8; ++j) { r0[j] = (u16)(vp[j] & 0xffffu); r1[j] = (u16)(vp[j] >> 16); }
            st_fragV(Vbuf[0], vd0,   vkb, r0);
            st_fragV(Vbuf[0], vd0+1, vkb, r1);
        }
        __syncthreads();

        f32x4 oT[4];
        #pragma unroll
        for (int nt = 0; nt < 4; ++nt) oT[nt] = (f32x4)(0.0f);
        float mrun = -1e30f, lrun = 0.0f;
        const int q_abs = qt0 + w*16 + lr;   // this lane's q row

        int cur = 0;
        for (int jt = 0; jt <= qtile; ++jt) {
            const bool pre = (jt < qtile);
            u16x8 kpre0, kpre1; unsigned vp[8];
            if (pre) {   // issue next-tile loads early (latency under compute)
                const int jn = (jt+1)*64;
                { int c = tid,     row = c >> 3, c8 = c & 7;
                  kpre0 = *reinterpret_cast<const u16x8*>(&Kbase[(size_t)(jn+row)*HD + c8*8]); }
                { int c = tid+256, row = c >> 3, c8 = c & 7;
                  kpre1 = *reinterpret_cast<const u16x8*>(&Kbase[(size_t)(jn+row)*HD + c8*8]); }
                #pragma unroll
                for (int j = 0; j < 8; ++j)
                    vp[j] = *reinterpret_cast<const unsigned*>(&Vbase[(size_t)(jn+vkb+j)*HD + vd0]);
            }

            const u16* Kc = Kbuf[cur];
            const u16* Vc = Vbuf[cur];

            // S^T = K Q^T : C row = key (lg*4+r), col = q (lr)
            f32x4 sT[4];
            #pragma unroll
            for (int nt = 0; nt < 4; ++nt) sT[nt] = (f32x4)(0.0f);
            #pragma unroll
            for (int ks = 0; ks < 2; ++ks) {
                bf16x8 qf = ld_frag(Qs, w*16 + lr, ks*32 + lg*8);
                #pragma unroll
                for (int nt = 0; nt < 4; ++nt)
                    sT[nt] = MFMA(ld_frag(Kc, nt*16 + lr, ks*32 + lg*8), qf, sT[nt]);
            }
            if (jt == qtile) {   // causal mask, diagonal tile only
                const int j0 = jt*64;
                #pragma unroll
                for (int nt = 0; nt < 4; ++nt)
                    #pragma unroll
                    for (int r = 0; r < 4; ++r)
                        if (j0 + nt*16 + lg*4 + r > q_abs) sT[nt][r] = -1e30f;
            }

            // online softmax, base 2, one q-row per lane
            float mx = -1e30f;
            #pragma unroll
            for (int nt = 0; nt < 4; ++nt)
                #pragma unroll
                for (int r = 0; r < 4; ++r) mx = fmaxf(mx, sT[nt][r]);
            mx = fmaxf(mx, __shfl_xor(mx, 16));
            mx = fmaxf(mx, __shfl_xor(mx, 32));
            float mnew = fmaxf(mrun, mx);
            float corr = exp2f(mrun - mnew);
            mrun = mnew;
            float rs = 0.0f;
            #pragma unroll
            for (int nt = 0; nt < 4; ++nt)
                #pragma unroll
                for (int r = 0; r < 4; ++r) {
                    float pv = exp2f(sT[nt][r] - mnew);
                    sT[nt][r] = pv;
                    rs += pv;
                }
            rs += __shfl_xor(rs, 16);
            rs += __shfl_xor(rs, 32);
            lrun = lrun*corr + rs;

            // P[q][key] -> per-wave LDS: 4 packed b64 (cols lg*4+r consecutive)
            u16* P = Ps[w];
            #pragma unroll
            for (int nt = 0; nt < 4; ++nt)
                st_b64(P, lr, nt*16 + lg*4, pack4(sT[nt]));

            #pragma unroll
            for (int nt = 0; nt < 4; ++nt)
                #pragma unroll
                for (int r = 0; r < 4; ++r) oT[nt][r] *= corr;

            // O^T += V^T P^T : C row = d (lg*4+r), col = q (lr)
            #pragma unroll
            for (int ks = 0; ks < 2; ++ks) {
                bf16x8 pf = ld_frag(P, lr, ks*32 + lg*8);
                #pragma unroll
                for (int nt = 0; nt < 4; ++nt)
                    oT[nt] = MFMA(ld_fragV(Vc, nt*16 + lr, ks*32 + lg*8), pf, oT[nt]);
            }

            if (pre) {   // drain prefetch into the other buffer
                u16* Kd = Kbuf[cur ^ 1];
                u16* Vd = Vbuf[cur ^ 1];
                { int c = tid,     row = c >> 3, c8 = c & 7; st_frag(Kd, row, c8*8, kpre0); }
                { int c = tid+256, row = c >> 3, c8 = c & 7; st_frag(Kd, row, c8*8, kpre1); }
                u16x8 r0, r1;
                #pragma unroll
                for (int j = 0; j < 8; ++j) { r0[j] = (u16)(vp[j] & 0xffffu); r1[j] = (u16)(vp[j] >> 16); }
                st_fragV(Vd, vd0,   vkb, r0);
                st_fragV(Vd, vd0+1, vkb, r1);
            }
            __syncthreads();
            cur ^= 1;
        }

        // epilogue: A[b][t][h*HD + d] = O/l ; lane-local q, 4-wide packed stores
        float inv = 1.0f / lrun;
        int t = qt0 + w*16 + lr;
        size_t base = ((size_t)b*SEQ + t)*NE + h*HD;
        #pragma unroll
        for (int nt = 0; nt < 4; ++nt) {
            f32x4 v;
            #pragma unroll
            for (int r = 0; r < 4; ++r) v[r] = oT[nt][r] * inv;
            *reinterpret_cast<u16x4*>(&Ab[base + nt*16 + lg*4]) = pack4(v);
        }
    }
}

// ---------------------------------------------------------------------------
// Output projection, plain bf16. out = A @ Wo.T + bo (fp32 out)
// ---------------------------------------------------------------------------
__global__ __launch_bounds__(256) void out_proj_kernel(
    const __bf16* __restrict__ Ab, const __bf16* __restrict__ wob,
    const float* __restrict__ bo, float* __restrict__ out)
{
    __shared__ __align__(16) u16 A_s[64*64], W_s[192*64];

    const int tid = threadIdx.x;
    const int m0 = blockIdx.x * 64;
    const int n0 = blockIdx.y * 192;
    const int w  = tid >> 6, l = tid & 63;
    const int lr = l & 15, lg = l >> 4;
    const __bf16* W = wob + (size_t)n0*NE;

    f32x4 acc[4][3];
    #pragma unroll
    for (int mt = 0; mt < 4; ++mt)
        #pragma unroll
        for (int nt = 0; nt < 3; ++nt) acc[mt][nt] = (f32x4)(0.0f);

    for (int k0 = 0; k0 < NE; k0 += 64) {
        __syncthreads();
        #pragma unroll
        for (int i = 0; i < 2; ++i) {
            int c = tid + i*256, row = c >> 3, c8 = c & 7;
            st_frag(A_s, row, c8*8, *reinterpret_cast<const u16x8*>(&Ab[(size_t)(m0+row)*NE + k0 + c8*8]));
        }
        #pragma unroll
        for (int i = 0; i < 6; ++i) {
            int c = tid + i*256, row = c >> 3, c8 = c & 7;
            st_frag(W_s, row, c8*8, *reinterpret_cast<const u16x8*>(&W[(size_t)row*NE + k0 + c8*8]));
        }
        __syncthreads();
        #pragma unroll
        for (int ks = 0; ks < 2; ++ks) {
            bf16x8 ah[4];
            #pragma unroll
            for (int mt = 0; mt < 4; ++mt)
                ah[mt] = ld_frag(A_s, mt*16 + lr, ks*32 + lg*8);
            #pragma unroll
            for (int nt = 0; nt < 3; ++nt) {
                bf16x8 wf = ld_frag(W_s, w*48 + nt*16 + lr, ks*32 + lg*8);
                #pragma unroll
                for (int mt = 0; mt < 4; ++mt)
                    acc[mt][nt] = MFMA(ah[mt], wf, acc[mt][nt]);
            }
        }
    }

    #pragma unroll
    for (int nt = 0; nt < 3; ++nt) {
        int col = n0 + w*48 + nt*16 + lr;
        float bb = bo[col];
        #pragma unroll
        for (int mt = 0; mt < 4; ++mt)
            #pragma unroll
            for (int r = 0; r < 4; ++r) {
                int m = m0 + mt*16 + lg*4 + r;
                out[(size_t)m*NE + col] = acc[mt][nt][r] + bb;
            }
    }
}

extern "C" void kernel_launch(void* const* d_in, const int* in_sizes, int n_in,
                              void* d_out, int out_size, void* d_ws, size_t ws_size,
                              hipStream_t stream)
{
    const float* x  = (const float*)d_in[0];
    // d_in[1] = attn_mask (tril) — causal structure known; unused.
    const float* Wq = (const float*)d_in[2];
    const float* bq = (const float*)d_in[3];
    const float* Wk = (const float*)d_in[4];
    const float* bk = (const float*)d_in[5];
    const float* Wv = (const float*)d_in[6];
    const float* bv = (const float*)d_in[7];
    const float* Wo = (const float*)d_in[8];
    const float* bo = (const float*)d_in[9];
    float* out = (float*)d_out;

    // ws layout (bf16 elements)
    __bf16* xb  = (__bf16*)d_ws;                 // MROWS*NE
    __bf16* wqb = xb  + (size_t)MROWS*NE;
    __bf16* wkb = wqb + 384*NE;
    __bf16* wvb = wkb + 192*NE;
    __bf16* wob = wvb + 192*NE;
    __bf16* Qb  = wob + 384*NE;                  // [B,NH,T,D], pre-scaled
    __bf16* Kb  = Qb + (size_t)BSZ*NH*SEQ*HD;
    __bf16* Vb  = Kb + (size_t)BSZ*NKV*SEQ*HD;
    __bf16* Ab  = xb;                            // alias: xb dead after qkv

    prep_kernel<<<dim3(256, 5), 256, 0, stream>>>(x, Wq, Wk, Wv, Wo,
                                                  xb, wqb, wkb, wvb, wob);
    qkv_proj_kernel<<<dim3(MROWS/64, 4), 256, 0, stream>>>(
        xb, wqb, wkb, wvb, bq, bk, bv, Qb, Kb, Vb);
    attn_kernel<<<dim3(NT_Q/2, NH, BSZ), 256, 0, stream>>>(Qb, Kb, Vb, Ab);
    out_proj_kernel<<<dim3(MROWS/64, 2), 256, 0, stream>>>(Ab, wob, bo, out);
}

// Round 7
// 202.468 us; speedup vs baseline: 5.2356x; 1.0377x over previous
//
#include <hip/hip_runtime.h>
#include <cstdint>
#include <cstddef>

#define NE   384
#define NH   6
#define NKV  3
#define HD   64
#define BSZ  8
#define SEQ  2048
#define MROWS (BSZ*SEQ)
#define NT_Q (SEQ/64)      // 32 q-tiles

typedef __bf16 bf16x8 __attribute__((ext_vector_type(8)));
typedef __bf16 bf16x4 __attribute__((ext_vector_type(4)));
typedef float  f32x4  __attribute__((ext_vector_type(4)));
typedef unsigned short u16;
typedef u16 u16x8 __attribute__((ext_vector_type(8)));
typedef u16 u16x4 __attribute__((ext_vector_type(4)));

#define MFMA(a,b,c) __builtin_amdgcn_mfma_f32_16x16x32_bf16((a),(b),(c),0,0,0)
// Q pre-scale: log2(e)/sqrt(384) — softmax done base-2 (v_exp_f32 is 2^x)
#define QSCALE (1.4426950408889634f * 0.05103103630798288f)

// ---- swizzled LDS tiles: row-major, row stride 128 B (64 bf16),
// ---- byte-in-row ^= (row&7)<<4  (conflict-free b128 column reads; G4/T2)
__device__ __forceinline__ bf16x8 ld_frag(const u16* lds, int row, int kk) {
    unsigned off = (unsigned)(row*128 + ((kk*2) ^ ((row&7)<<4)));
    return *reinterpret_cast<const bf16x8*>(reinterpret_cast<const char*>(lds) + off);
}
__device__ __forceinline__ void st_frag(u16* lds, int row, int kk, u16x8 v) {
    unsigned off = (unsigned)(row*128 + ((kk*2) ^ ((row&7)<<4)));
    *reinterpret_cast<u16x8*>(reinterpret_cast<char*>(lds) + off) = v;
}
// packed b64 store into a (row&7)-swizzled tile (8B offsets stay 8-aligned)
__device__ __forceinline__ void st_b64(u16* lds, int row, int col, u16x4 v) {
    unsigned off = (unsigned)(row*128 + ((col*2) ^ ((row&7)<<4)));
    *reinterpret_cast<u16x4*>(reinterpret_cast<char*>(lds) + off) = v;
}
__device__ __forceinline__ u16x4 pack4(f32x4 v) {
    bf16x4 h;
    h[0] = (__bf16)v[0]; h[1] = (__bf16)v[1]; h[2] = (__bf16)v[2]; h[3] = (__bf16)v[3];
    return *reinterpret_cast<u16x4*>(&h);
}

// ---------------------------------------------------------------------------
// Prep: fp32 -> bf16 for x and all weights.
// ---------------------------------------------------------------------------
__global__ __launch_bounds__(256) void prep_kernel(
    const float* __restrict__ x,  const float* __restrict__ Wq,
    const float* __restrict__ Wk, const float* __restrict__ Wv,
    const float* __restrict__ Wo,
    __bf16* xb, __bf16* wqb, __bf16* wkb, __bf16* wvb, __bf16* wob)
{
    const float* src; __bf16* dst; int n4;
    switch (blockIdx.y) {
        case 0:  src = x;  dst = xb;  n4 = MROWS*NE/4; break;
        case 1:  src = Wq; dst = wqb; n4 = 384*NE/4;   break;
        case 2:  src = Wk; dst = wkb; n4 = 192*NE/4;   break;
        case 3:  src = Wv; dst = wvb; n4 = 192*NE/4;   break;
        default: src = Wo; dst = wob; n4 = 384*NE/4;   break;
    }
    for (int i = blockIdx.x*256 + threadIdx.x; i < n4; i += gridDim.x*256) {
        float4 v = reinterpret_cast<const float4*>(src)[i];
        bf16x4 h;
        h[0] = (__bf16)v.x; h[1] = (__bf16)v.y; h[2] = (__bf16)v.z; h[3] = (__bf16)v.w;
        reinterpret_cast<bf16x4*>(dst)[i] = h;
    }
}

// ---------------------------------------------------------------------------
// QKV projection, plain bf16. BM=32, BN=192, BK=64, 4 waves; wave w owns
// 32 rows x cols [w*48, w*48+48). LDS 28 KB -> 5 blocks/CU, grid 2048.
// V is written TRANSPOSED [B,KV,D,T] so attn stages it like K (no repack).
// ---------------------------------------------------------------------------
__global__ __launch_bounds__(256) void qkv_proj_kernel(
    const __bf16* __restrict__ xb,
    const __bf16* __restrict__ wqb, const __bf16* __restrict__ wkb,
    const __bf16* __restrict__ wvb,
    const float* __restrict__ bq, const float* __restrict__ bk,
    const float* __restrict__ bv,
    __bf16* __restrict__ Qb, __bf16* __restrict__ Kb, __bf16* __restrict__ Vt)
{
    __shared__ __align__(16) u16 A_s[32*64], W_s[192*64];   // 4 + 24 KB

    const int tid = threadIdx.x;
    const int m0 = blockIdx.x * 32;
    const int w  = tid >> 6, l = tid & 63;
    const int lr = l & 15, lg = l >> 4;

    const __bf16* W; const float* bias; int outsel, colbase;
    if (blockIdx.y == 0)      { W = wqb;          bias = bq; outsel = 0; colbase = 0;   }
    else if (blockIdx.y == 1) { W = wqb + 192*NE; bias = bq; outsel = 0; colbase = 192; }
    else if (blockIdx.y == 2) { W = wkb;          bias = bk; outsel = 1; colbase = 0;   }
    else                      { W = wvb;          bias = bv; outsel = 2; colbase = 0;   }

    f32x4 acc[2][3];
    #pragma unroll
    for (int mt = 0; mt < 2; ++mt)
        #pragma unroll
        for (int nt = 0; nt < 3; ++nt) acc[mt][nt] = (f32x4)(0.0f);

    for (int k0 = 0; k0 < NE; k0 += 64) {
        __syncthreads();
        {   // A: 32 rows x 8 chunks = 256 = one pass
            int row = tid >> 3, c8 = tid & 7;
            st_frag(A_s, row, c8*8, *reinterpret_cast<const u16x8*>(&xb[(size_t)(m0+row)*NE + k0 + c8*8]));
        }
        #pragma unroll
        for (int i = 0; i < 6; ++i) {   // W: 192 rows x 8 chunks = 1536
            int c = tid + i*256, row = c >> 3, c8 = c & 7;
            st_frag(W_s, row, c8*8, *reinterpret_cast<const u16x8*>(&W[(size_t)row*NE + k0 + c8*8]));
        }
        __syncthreads();
        #pragma unroll
        for (int ks = 0; ks < 2; ++ks) {
            bf16x8 ah[2];
            #pragma unroll
            for (int mt = 0; mt < 2; ++mt)
                ah[mt] = ld_frag(A_s, mt*16 + lr, ks*32 + lg*8);
            #pragma unroll
            for (int nt = 0; nt < 3; ++nt) {
                bf16x8 wf = ld_frag(W_s, w*48 + nt*16 + lr, ks*32 + lg*8);
                #pragma unroll
                for (int mt = 0; mt < 2; ++mt)
                    acc[mt][nt] = MFMA(ah[mt], wf, acc[mt][nt]);
            }
        }
    }

    #pragma unroll
    for (int nt = 0; nt < 3; ++nt) {
        int colt = colbase + w*48 + nt*16 + lr;
        float bb = bias[colt];
        int hh = colt >> 6, dd = colt & 63;
        #pragma unroll
        for (int mt = 0; mt < 2; ++mt) {
            int mbase = m0 + mt*16 + lg*4;
            int b8 = mbase >> 11, t0 = mbase & 2047;   // 4 rows same batch (32-aligned)
            if (outsel == 0) {
                #pragma unroll
                for (int r = 0; r < 4; ++r)
                    Qb[(((size_t)b8*NH + hh)*SEQ + t0 + r)*HD + dd] =
                        (__bf16)((acc[mt][nt][r] + bb) * QSCALE);
            } else if (outsel == 1) {
                #pragma unroll
                for (int r = 0; r < 4; ++r)
                    Kb[(((size_t)b8*NKV + hh)*SEQ + t0 + r)*HD + dd] =
                        (__bf16)(acc[mt][nt][r] + bb);
            } else {
                // V transposed: [B,KV,D,T]; 4 consecutive t -> packed 8B store
                f32x4 v;
                #pragma unroll
                for (int r = 0; r < 4; ++r) v[r] = acc[mt][nt][r] + bb;
                *reinterpret_cast<u16x4*>(
                    &Vt[(((size_t)b8*NKV + hh)*HD + dd)*SEQ + t0]) = pack4(v);
            }
        }
    }
}

// ---------------------------------------------------------------------------
// Flash attention, swapped-operand (lane-local softmax), bf16 MFMA.
//   S^T = mfma(K, Q): lane q = lr, 16 keys in-register
//   Q held in registers (2 frags/pass) — no Q LDS
//   rs (softmax denom) via ones-MFMA on the idle matrix pipe
//   defer-max: skip O-rescale while max grows < 8 (base-2, T13)
//   V comes pre-transposed [B,KV,D,T] -> staged exactly like K
// Block = (pair p, h, b): q-tiles p and 31-p -> uniform 33 kv-iterations.
// K/V double-buffered, prefetch issued before compute, 1 barrier/iter.
// ---------------------------------------------------------------------------
__global__ __launch_bounds__(256) void attn_kernel(
    const __bf16* __restrict__ Qb, const __bf16* __restrict__ Kb,
    const __bf16* __restrict__ Vt, __bf16* __restrict__ Ab)
{
    __shared__ __align__(16) u16 Kbuf[2][64*64];
    __shared__ __align__(16) u16 Vbuf[2][64*64];
    __shared__ __align__(16) u16 Ps[4][16*64];     // 40 KB total

    const int tid = threadIdx.x;
    const int w  = tid >> 6, l = tid & 63;
    const int lr = l & 15, lg = l >> 4;
    const int p = blockIdx.x, h = blockIdx.y, b = blockIdx.z;
    const int kvh = h >> 1;                        // interleaved repeat_kv

    const __bf16* Kbase = Kb + ((size_t)b*NKV + kvh)*SEQ*HD;
    const __bf16* Vbase = Vt + ((size_t)b*NKV + kvh)*HD*SEQ;   // [D][T]

    const int srow = tid >> 3, sc8 = tid & 7;      // staging coords (K/V alike)

    bf16x8 ones;
    #pragma unroll
    for (int j = 0; j < 8; ++j) ones[j] = (__bf16)1.0f;

    for (int pass = 0; pass < 2; ++pass) {
        const int qtile = pass ? (NT_Q-1-p) : p;
        const int qt0 = qtile * 64;
        const __bf16* Qbase = Qb + (((size_t)b*NH + h)*SEQ + qt0)*HD;

        // Q fragments straight to registers (wave-private rows)
        const __bf16* qrow = Qbase + (size_t)(w*16 + lr)*HD + lg*8;
        bf16x8 qf0 = *reinterpret_cast<const bf16x8*>(qrow);
        bf16x8 qf1 = *reinterpret_cast<const bf16x8*>(qrow + 32);

        // stage K/V tile 0 -> buf 0 (V rows are d, contiguous keys)
        st_frag(Kbuf[0], srow, sc8*8, *reinterpret_cast<const u16x8*>(&Kbase[(size_t)srow*HD + sc8*8]));
        st_frag(Kbuf[0], srow+32, sc8*8, *reinterpret_cast<const u16x8*>(&Kbase[(size_t)(srow+32)*HD + sc8*8]));
        st_frag(Vbuf[0], srow, sc8*8, *reinterpret_cast<const u16x8*>(&Vbase[(size_t)srow*SEQ + sc8*8]));
        st_frag(Vbuf[0], srow+32, sc8*8, *reinterpret_cast<const u16x8*>(&Vbase[(size_t)(srow+32)*SEQ + sc8*8]));
        __syncthreads();

        f32x4 oT[4];
        #pragma unroll
        for (int nt = 0; nt < 4; ++nt) oT[nt] = (f32x4)(0.0f);
        float mrun = -1e30f, lrun = 0.0f;
        const int q_abs = qt0 + w*16 + lr;   // this lane's q row

        int cur = 0;
        for (int jt = 0; jt <= qtile; ++jt) {
            const bool pre = (jt < qtile);
            u16x8 kpre0, kpre1, vpre0, vpre1;
            if (pre) {   // issue next-tile loads early (latency under compute)
                const int jn = (jt+1)*64;
                kpre0 = *reinterpret_cast<const u16x8*>(&Kbase[(size_t)(jn+srow)*HD + sc8*8]);
                kpre1 = *reinterpret_cast<const u16x8*>(&Kbase[(size_t)(jn+srow+32)*HD + sc8*8]);
                vpre0 = *reinterpret_cast<const u16x8*>(&Vbase[(size_t)srow*SEQ + jn + sc8*8]);
                vpre1 = *reinterpret_cast<const u16x8*>(&Vbase[(size_t)(srow+32)*SEQ + jn + sc8*8]);
            }

            const u16* Kc = Kbuf[cur];
            const u16* Vc = Vbuf[cur];

            // S^T = K Q^T : C row = key (lg*4+r), col = q (lr)
            f32x4 sT[4];
            #pragma unroll
            for (int nt = 0; nt < 4; ++nt) sT[nt] = (f32x4)(0.0f);
            #pragma unroll
            for (int nt = 0; nt < 4; ++nt) {
                sT[nt] = MFMA(ld_frag(Kc, nt*16 + lr, lg*8), qf0, sT[nt]);
                sT[nt] = MFMA(ld_frag(Kc, nt*16 + lr, 32 + lg*8), qf1, sT[nt]);
            }
            if (jt == qtile) {   // causal mask, diagonal tile only
                const int j0 = jt*64;
                #pragma unroll
                for (int nt = 0; nt < 4; ++nt)
                    #pragma unroll
                    for (int r = 0; r < 4; ++r)
                        if (j0 + nt*16 + lg*4 + r > q_abs) sT[nt][r] = -1e30f;
            }

            // lane-local max (tree; max3-fusable)
            float mxa = fmaxf(fmaxf(sT[0][0], sT[0][1]), fmaxf(sT[0][2], sT[0][3]));
            float mxb = fmaxf(fmaxf(sT[1][0], sT[1][1]), fmaxf(sT[1][2], sT[1][3]));
            float mxc = fmaxf(fmaxf(sT[2][0], sT[2][1]), fmaxf(sT[2][2], sT[2][3]));
            float mxd = fmaxf(fmaxf(sT[3][0], sT[3][1]), fmaxf(sT[3][2], sT[3][3]));
            float mx = fmaxf(fmaxf(mxa, mxb), fmaxf(mxc, mxd));
            mx = fmaxf(mx, __shfl_xor(mx, 16));
            mx = fmaxf(mx, __shfl_xor(mx, 32));

            // defer-max (T13): rescale only when the running max grew > 8
            if (!__all(mx - mrun <= 8.0f)) {
                float mnew = fmaxf(mrun, mx);
                float corr = exp2f(mrun - mnew);
                mrun = mnew;
                lrun *= corr;
                #pragma unroll
                for (int nt = 0; nt < 4; ++nt)
                    #pragma unroll
                    for (int r = 0; r < 4; ++r) oT[nt][r] *= corr;
            }

            // P = exp2(S - mrun), packed to bf16, 4x b64 into per-wave LDS
            u16* P = Ps[w];
            #pragma unroll
            for (int nt = 0; nt < 4; ++nt) {
                f32x4 pv;
                #pragma unroll
                for (int r = 0; r < 4; ++r) pv[r] = exp2f(sT[nt][r] - mrun);
                st_b64(P, lr, nt*16 + lg*4, pack4(pv));
            }

            // O^T += V^T P^T ; rs via ones-MFMA (all C rows = row-sum of P)
            f32x4 rsacc = (f32x4)(0.0f);
            #pragma unroll
            for (int ks = 0; ks < 2; ++ks) {
                bf16x8 pf = ld_frag(P, lr, ks*32 + lg*8);
                rsacc = MFMA(ones, pf, rsacc);
                #pragma unroll
                for (int nt = 0; nt < 4; ++nt)
                    oT[nt] = MFMA(ld_frag(Vc, nt*16 + lr, ks*32 + lg*8), pf, oT[nt]);
            }
            lrun += rsacc[0];

            if (pre) {   // drain prefetch into the other buffer
                u16* Kd = Kbuf[cur ^ 1];
                u16* Vd = Vbuf[cur ^ 1];
                st_frag(Kd, srow,    sc8*8, kpre0);
                st_frag(Kd, srow+32, sc8*8, kpre1);
                st_frag(Vd, srow,    sc8*8, vpre0);
                st_frag(Vd, srow+32, sc8*8, vpre1);
            }
            __syncthreads();
            cur ^= 1;
        }

        // epilogue: A[b][t][h*HD+d] = O/l ; lane-local q, packed 8B stores
        float inv = 1.0f / lrun;
        int t = qt0 + w*16 + lr;
        size_t base = ((size_t)b*SEQ + t)*NE + h*HD;
        #pragma unroll
        for (int nt = 0; nt < 4; ++nt) {
            f32x4 v;
            #pragma unroll
            for (int r = 0; r < 4; ++r) v[r] = oT[nt][r] * inv;
            *reinterpret_cast<u16x4*>(&Ab[base + nt*16 + lg*4]) = pack4(v);
        }
    }
}

// ---------------------------------------------------------------------------
// Output projection, plain bf16. BM=32, BN=192. out = A @ Wo.T + bo (fp32)
// ---------------------------------------------------------------------------
__global__ __launch_bounds__(256) void out_proj_kernel(
    const __bf16* __restrict__ Ab, const __bf16* __restrict__ wob,
    const float* __restrict__ bo, float* __restrict__ out)
{
    __shared__ __align__(16) u16 A_s[32*64], W_s[192*64];

    const int tid = threadIdx.x;
    const int m0 = blockIdx.x * 32;
    const int n0 = blockIdx.y * 192;
    const int w  = tid >> 6, l = tid & 63;
    const int lr = l & 15, lg = l >> 4;
    const __bf16* W = wob + (size_t)n0*NE;

    f32x4 acc[2][3];
    #pragma unroll
    for (int mt = 0; mt < 2; ++mt)
        #pragma unroll
        for (int nt = 0; nt < 3; ++nt) acc[mt][nt] = (f32x4)(0.0f);

    for (int k0 = 0; k0 < NE; k0 += 64) {
        __syncthreads();
        {
            int row = tid >> 3, c8 = tid & 7;
            st_frag(A_s, row, c8*8, *reinterpret_cast<const u16x8*>(&Ab[(size_t)(m0+row)*NE + k0 + c8*8]));
        }
        #pragma unroll
        for (int i = 0; i < 6; ++i) {
            int c = tid + i*256, row = c >> 3, c8 = c & 7;
            st_frag(W_s, row, c8*8, *reinterpret_cast<const u16x8*>(&W[(size_t)row*NE + k0 + c8*8]));
        }
        __syncthreads();
        #pragma unroll
        for (int ks = 0; ks < 2; ++ks) {
            bf16x8 ah[2];
            #pragma unroll
            for (int mt = 0; mt < 2; ++mt)
                ah[mt] = ld_frag(A_s, mt*16 + lr, ks*32 + lg*8);
            #pragma unroll
            for (int nt = 0; nt < 3; ++nt) {
                bf16x8 wf = ld_frag(W_s, w*48 + nt*16 + lr, ks*32 + lg*8);
                #pragma unroll
                for (int mt = 0; mt < 2; ++mt)
                    acc[mt][nt] = MFMA(ah[mt], wf, acc[mt][nt]);
            }
        }
    }

    #pragma unroll
    for (int nt = 0; nt < 3; ++nt) {
        int col = n0 + w*48 + nt*16 + lr;
        float bb = bo[col];
        #pragma unroll
        for (int mt = 0; mt < 2; ++mt)
            #pragma unroll
            for (int r = 0; r < 4; ++r) {
                int m = m0 + mt*16 + lg*4 + r;
                out[(size_t)m*NE + col] = acc[mt][nt][r] + bb;
            }
    }
}

extern "C" void kernel_launch(void* const* d_in, const int* in_sizes, int n_in,
                              void* d_out, int out_size, void* d_ws, size_t ws_size,
                              hipStream_t stream)
{
    const float* x  = (const float*)d_in[0];
    // d_in[1] = attn_mask (tril) — causal structure known; unused.
    const float* Wq = (const float*)d_in[2];
    const float* bq = (const float*)d_in[3];
    const float* Wk = (const float*)d_in[4];
    const float* bk = (const float*)d_in[5];
    const float* Wv = (const float*)d_in[6];
    const float* bv = (const float*)d_in[7];
    const float* Wo = (const float*)d_in[8];
    const float* bo = (const float*)d_in[9];
    float* out = (float*)d_out;

    // ws layout (bf16 elements)
    __bf16* xb  = (__bf16*)d_ws;                 // MROWS*NE
    __bf16* wqb = xb  + (size_t)MROWS*NE;
    __bf16* wkb = wqb + 384*NE;
    __bf16* wvb = wkb + 192*NE;
    __bf16* wob = wvb + 192*NE;
    __bf16* Qb  = wob + 384*NE;                  // [B,NH,T,D], pre-scaled
    __bf16* Kb  = Qb + (size_t)BSZ*NH*SEQ*HD;    // [B,KV,T,D]
    __bf16* Vt  = Kb + (size_t)BSZ*NKV*SEQ*HD;   // [B,KV,D,T]  (transposed!)
    __bf16* Ab  = xb;                            // alias: xb dead after qkv

    prep_kernel<<<dim3(256, 5), 256, 0, stream>>>(x, Wq, Wk, Wv, Wo,
                                                  xb, wqb, wkb, wvb, wob);
    qkv_proj_kernel<<<dim3(MROWS/32, 4), 256, 0, stream>>>(
        xb, wqb, wkb, wvb, bq, bk, bv, Qb, Kb, Vt);
    attn_kernel<<<dim3(NT_Q/2, NH, BSZ), 256, 0, stream>>>(Qb, Kb, Vt, Ab);
    out_proj_kernel<<<dim3(MROWS/32, 2), 256, 0, stream>>>(Ab, wob, bo, out);
}